// Round 9
// baseline (283.603 us; speedup 1.0000x reference)
//
#include <hip/hip_runtime.h>
#include <hip/hip_bf16.h>
#include <stdint.h>

// Problem constants
constexpr int B    = 8;
constexpr int T    = 2048;
constexpr int EMB  = 2048;
constexpr int HD   = 128;
constexpr int M    = B * T;        // 16384 rows for projection GEMM
constexpr int NW   = 3 * HD;       // 384 fused output cols (Q|K|V)

typedef __attribute__((ext_vector_type(8))) short short8;
typedef __attribute__((ext_vector_type(4))) float f32x4;

__device__ inline unsigned short f2bf(float f) {
    union { float f; unsigned int u; } v; v.f = f;
    unsigned int x = v.u;
    unsigned int r = (x + 0x7FFFu + ((x >> 16) & 1u)) >> 16;   // RNE
    return (unsigned short)r;
}

__device__ inline unsigned int cvt_pk_bf16(float a, float b) {
    unsigned int r;
    asm volatile("v_cvt_pk_bf16_f32 %0, %1, %2" : "=v"(r) : "v"(a), "v"(b));
    return r;   // lo = bf16(a), hi = bf16(b)
}

// ---------------------------------------------------------------------------
// Kernel 0: convert Wq|Wk|Wv fp32 -> bf16 into Wb[384][2048]
// ---------------------------------------------------------------------------
__global__ __launch_bounds__(256) void conv_w(
    const float* __restrict__ Wq, const float* __restrict__ Wk, const float* __restrict__ Wv,
    unsigned short* __restrict__ Wb)
{
    int base = (blockIdx.x * 256 + threadIdx.x) * 8;   // < 384*2048
    int row = base >> 11, col = base & 2047;
    const float* src;
    if (row < 128)      src = Wq + (size_t)row * EMB + col;
    else if (row < 256) src = Wk + (size_t)(row - 128) * EMB + col;
    else                src = Wv + (size_t)(row - 256) * EMB + col;
    float4 a = *(const float4*)src;
    float4 b = *(const float4*)(src + 4);
    short8 sv;
    sv[0] = f2bf(a.x); sv[1] = f2bf(a.y); sv[2] = f2bf(a.z); sv[3] = f2bf(a.w);
    sv[4] = f2bf(b.x); sv[5] = f2bf(b.y); sv[6] = f2bf(b.z); sv[7] = f2bf(b.w);
    *(short8*)(Wb + base) = sv;
}

// ---------------------------------------------------------------------------
// Kernel 1: fused QKV projection — UNCHANGED from R8 (baseline for ablation).
// ---------------------------------------------------------------------------
constexpr int PBM = 64;
constexpr int PBK = 64;
constexpr int PNT = EMB / PBK;   // 32

__global__ __launch_bounds__(512) void qkv_proj(
    const float* __restrict__ x, const unsigned short* __restrict__ Wb,
    unsigned short* __restrict__ Qb, unsigned short* __restrict__ Kb,
    unsigned short* __restrict__ VtG)
{
    __shared__ unsigned short Asm[2][PBM * PBK];   // 2 x 8 KB
    __shared__ unsigned short Bsm[2][NW * PBK];    // 2 x 48 KB

    const int m0   = blockIdx.x * PBM;
    const int tid  = threadIdx.x;
    const int lane = tid & 63;
    const int w    = tid >> 6;           // 0..7
    const int wr   = w >> 2;             // 0..1 (32-row group)
    const int wc   = w & 3;              // 0..3 (96-col group)
    const int lo   = lane & 15;
    const int hi   = lane >> 4;

    const int ar = tid >> 3;
    const int as = tid & 7;
    const float* asrc = x + (size_t)(m0 + ar) * EMB + as * 8;

    f32x4 acc[2][6];
#pragma unroll
    for (int i = 0; i < 2; ++i)
#pragma unroll
        for (int j = 0; j < 6; ++j) acc[i][j] = (f32x4)0.0f;

    float4 a0, a1;
    auto issueA = [&](int k0) {
        a0 = *(const float4*)(asrc + k0);
        a1 = *(const float4*)(asrc + k0 + 4);
    };
    auto writeA = [&](int buf) {
        uint4 p;
        p.x = cvt_pk_bf16(a0.x, a0.y);
        p.y = cvt_pk_bf16(a0.z, a0.w);
        p.z = cvt_pk_bf16(a1.x, a1.y);
        p.w = cvt_pk_bf16(a1.z, a1.w);
        int ps = as ^ (ar & 7);
        *(uint4*)&Asm[buf][ar * PBK + ps * 8] = p;
    };
    auto stageB = [&](int k0, int buf) {
#pragma unroll
        for (int it = 0; it < 6; ++it) {
            int c = it * 512 + tid;
            int row = c >> 3;
            int lseg = (c & 7) ^ (row & 7);
            __builtin_amdgcn_global_load_lds(
                (const __attribute__((address_space(1))) unsigned int*)
                    (Wb + (size_t)row * EMB + k0 + lseg * 8),
                (__attribute__((address_space(3))) unsigned int*)
                    ((char*)&Bsm[buf][0] + (it * 512 + w * 64) * 16),
                16, 0, 0);
        }
    };
    auto compute = [&](int buf) {
#pragma unroll
        for (int kk = 0; kk < 2; ++kk) {
            short8 af[2], bf[6];
#pragma unroll
            for (int i = 0; i < 2; ++i) {
                int R = wr * 32 + i * 16 + lo;
                int pseg = (kk * 4 + hi) ^ (R & 7);
                af[i] = *(const short8*)&Asm[buf][R * PBK + pseg * 8];
            }
#pragma unroll
            for (int j = 0; j < 6; ++j) {
                int n = wc * 96 + j * 16 + lo;
                int pseg = (kk * 4 + hi) ^ (n & 7);
                bf[j] = *(const short8*)&Bsm[buf][n * PBK + pseg * 8];
            }
#pragma unroll
            for (int i = 0; i < 2; ++i)
#pragma unroll
                for (int j = 0; j < 6; ++j)
                    acc[i][j] = __builtin_amdgcn_mfma_f32_16x16x32_bf16(af[i], bf[j], acc[i][j], 0, 0, 0);
        }
    };

    issueA(0);
    stageB(0, 0);
    writeA(0);
    asm volatile("s_waitcnt vmcnt(0) lgkmcnt(0)" ::: "memory");
    __builtin_amdgcn_s_barrier();

    for (int t = 0; t < PNT; ++t) {
        const int buf = t & 1;
        if (t + 1 < PNT) {
            issueA((t + 1) * PBK);
            stageB((t + 1) * PBK, buf ^ 1);
        }
        compute(buf);
        if (t + 1 < PNT) {
            writeA(buf ^ 1);
            asm volatile("s_waitcnt vmcnt(0) lgkmcnt(0)" ::: "memory");
            __builtin_amdgcn_s_barrier();
        }
    }

    const int b = m0 >> 11;
#pragma unroll
    for (int i = 0; i < 2; ++i) {
        int mrow0 = m0 + wr * 32 + i * 16 + hi * 4;
#pragma unroll
        for (int j = 0; j < 6; ++j) {
            int cw = wc * 6 + j;
            int colbase = cw * 16 + lo;
            if (cw < 8) {                      // Q
#pragma unroll
                for (int r = 0; r < 4; ++r)
                    Qb[(size_t)(mrow0 + r) * HD + colbase] = f2bf(acc[i][j][r]);
            } else if (cw < 16) {              // K
#pragma unroll
                for (int r = 0; r < 4; ++r)
                    Kb[(size_t)(mrow0 + r) * HD + (colbase - 128)] = f2bf(acc[i][j][r]);
            } else {                           // V -> transposed [B][HD][T]
                int h = colbase - 256;
                int tloc = mrow0 - b * T;
                ushort4 pv;
                pv.x = f2bf(acc[i][j][0]); pv.y = f2bf(acc[i][j][1]);
                pv.z = f2bf(acc[i][j][2]); pv.w = f2bf(acc[i][j][3]);
                *(ushort4*)(VtG + ((size_t)(b * HD + h)) * T + tloc) = pv;
            }
        }
    }
}

// ---------------------------------------------------------------------------
// DIAGNOSTIC 1: stage-only, 96 steps (3x real loop). Same LDS/occupancy/grid
// as qkv_proj. Measures {issueA + B-DMA + writeA + vmcnt(0) + barrier} alone.
// Visible in top-5 iff per-32-step staging cost > ~28 us.
// ---------------------------------------------------------------------------
constexpr int DSTEPS = 96;

__global__ __launch_bounds__(512) void diag_stage(
    const float* __restrict__ x, const unsigned short* __restrict__ Wb,
    float* __restrict__ scr)
{
    __shared__ unsigned short Asm[2][PBM * PBK];
    __shared__ unsigned short Bsm[2][NW * PBK];

    const int m0  = blockIdx.x * PBM;
    const int tid = threadIdx.x;
    const int w   = tid >> 6;
    const int ar  = tid >> 3;
    const int as  = tid & 7;
    const float* asrc = x + (size_t)(m0 + ar) * EMB + as * 8;

    float4 a0, a1;
#pragma unroll 1
    for (int t = 0; t < DSTEPS; ++t) {
        const int k0  = (t & 31) * PBK;
        const int buf = t & 1;
        a0 = *(const float4*)(asrc + k0);
        a1 = *(const float4*)(asrc + k0 + 4);
#pragma unroll
        for (int it = 0; it < 6; ++it) {
            int c = it * 512 + tid;
            int row = c >> 3;
            int lseg = (c & 7) ^ (row & 7);
            __builtin_amdgcn_global_load_lds(
                (const __attribute__((address_space(1))) unsigned int*)
                    (Wb + (size_t)row * EMB + k0 + lseg * 8),
                (__attribute__((address_space(3))) unsigned int*)
                    ((char*)&Bsm[buf][0] + (it * 512 + w * 64) * 16),
                16, 0, 0);
        }
        {
            uint4 p;
            p.x = cvt_pk_bf16(a0.x, a0.y);
            p.y = cvt_pk_bf16(a0.z, a0.w);
            p.z = cvt_pk_bf16(a1.x, a1.y);
            p.w = cvt_pk_bf16(a1.z, a1.w);
            int ps = as ^ (ar & 7);
            *(uint4*)&Asm[buf][ar * PBK + ps * 8] = p;
        }
        asm volatile("s_waitcnt vmcnt(0) lgkmcnt(0)" ::: "memory");
        __builtin_amdgcn_s_barrier();
    }
    // keep staged data live
    float v = *(const float*)&Bsm[0][tid * 8] + *(const float*)&Asm[0][(tid & 255) * 8];
    scr[(size_t)blockIdx.x * 512 + tid] = v;
}

// ---------------------------------------------------------------------------
// DIAGNOSTIC 2: compute-only, 96 steps. Stage both buffers once, then loop
// {ds_read frags + 24 MFMA + barrier}. Measures the compute phase alone.
// ---------------------------------------------------------------------------
__global__ __launch_bounds__(512) void diag_compute(
    const float* __restrict__ x, const unsigned short* __restrict__ Wb,
    float* __restrict__ scr)
{
    __shared__ unsigned short Asm[2][PBM * PBK];
    __shared__ unsigned short Bsm[2][NW * PBK];

    const int m0   = blockIdx.x * PBM;
    const int tid  = threadIdx.x;
    const int lane = tid & 63;
    const int w    = tid >> 6;
    const int wr   = w >> 2;
    const int wc   = w & 3;
    const int lo   = lane & 15;
    const int hi   = lane >> 4;
    const int ar   = tid >> 3;
    const int as   = tid & 7;
    const float* asrc = x + (size_t)(m0 + ar) * EMB + as * 8;

    // prologue: stage BOTH buffers (defined data everywhere)
#pragma unroll
    for (int bufp = 0; bufp < 2; ++bufp) {
        int k0 = bufp * PBK;
#pragma unroll
        for (int it = 0; it < 6; ++it) {
            int c = it * 512 + tid;
            int row = c >> 3;
            int lseg = (c & 7) ^ (row & 7);
            __builtin_amdgcn_global_load_lds(
                (const __attribute__((address_space(1))) unsigned int*)
                    (Wb + (size_t)row * EMB + k0 + lseg * 8),
                (__attribute__((address_space(3))) unsigned int*)
                    ((char*)&Bsm[bufp][0] + (it * 512 + w * 64) * 16),
                16, 0, 0);
        }
        float4 a0 = *(const float4*)(asrc + k0);
        float4 a1 = *(const float4*)(asrc + k0 + 4);
        uint4 p;
        p.x = cvt_pk_bf16(a0.x, a0.y);
        p.y = cvt_pk_bf16(a0.z, a0.w);
        p.z = cvt_pk_bf16(a1.x, a1.y);
        p.w = cvt_pk_bf16(a1.z, a1.w);
        int ps = as ^ (ar & 7);
        *(uint4*)&Asm[bufp][ar * PBK + ps * 8] = p;
    }
    asm volatile("s_waitcnt vmcnt(0) lgkmcnt(0)" ::: "memory");
    __builtin_amdgcn_s_barrier();

    f32x4 acc[2][6];
#pragma unroll
    for (int i = 0; i < 2; ++i)
#pragma unroll
        for (int j = 0; j < 6; ++j) acc[i][j] = (f32x4)0.0f;

#pragma unroll 1
    for (int t = 0; t < DSTEPS; ++t) {
        const int buf = t & 1;
#pragma unroll
        for (int kk = 0; kk < 2; ++kk) {
            short8 af[2], bf[6];
#pragma unroll
            for (int i = 0; i < 2; ++i) {
                int R = wr * 32 + i * 16 + lo;
                int pseg = (kk * 4 + hi) ^ (R & 7);
                af[i] = *(const short8*)&Asm[buf][R * PBK + pseg * 8];
            }
#pragma unroll
            for (int j = 0; j < 6; ++j) {
                int n = wc * 96 + j * 16 + lo;
                int pseg = (kk * 4 + hi) ^ (n & 7);
                bf[j] = *(const short8*)&Bsm[buf][n * PBK + pseg * 8];
            }
#pragma unroll
            for (int i = 0; i < 2; ++i)
#pragma unroll
                for (int j = 0; j < 6; ++j)
                    acc[i][j] = __builtin_amdgcn_mfma_f32_16x16x32_bf16(af[i], bf[j], acc[i][j], 0, 0, 0);
        }
        __builtin_amdgcn_s_barrier();
    }

    float s = 0.0f;
#pragma unroll
    for (int i = 0; i < 2; ++i)
#pragma unroll
        for (int j = 0; j < 6; ++j)
#pragma unroll
            for (int r = 0; r < 4; ++r) s += acc[i][j][r];
    scr[(size_t)blockIdx.x * 512 + tid] = s;
}

// ---------------------------------------------------------------------------
// Kernel 2: causal flash attention with KV-split (flash-decoding style).
// ---------------------------------------------------------------------------
constexpr int QB = 64;
constexpr int KB = 64;
constexpr int STILES = 8;   // kv tiles per split block

__global__ __launch_bounds__(256) void attn_fwd(
    const unsigned short* __restrict__ Qb,
    const unsigned short* __restrict__ Kb,
    const unsigned short* __restrict__ VtG,
    float* __restrict__ out,
    float* __restrict__ part_o, float* __restrict__ part_ml,
    int use_split)
{
    const int b  = blockIdx.y;
    int bx = blockIdx.x;
    int qt, s, nsplit;
    if (use_split) {
        if (bx < 8)       { qt = bx;               s = 0; }
        else if (bx < 24) { qt = 8  + (bx - 8) / 2;  s = (bx - 8) & 1; }
        else if (bx < 48) { qt = 16 + (bx - 24) / 3; s = (bx - 24) % 3; }
        else              { qt = 24 + (bx - 48) / 4; s = (bx - 48) & 3; }
        nsplit = qt / 8 + 1;
    } else {
        qt = bx; s = 0; nsplit = 1;
    }
    const int q0 = qt * QB;
    int t0 = s * STILES;
    int t1 = t0 + STILES; if (t1 > qt + 1) t1 = qt + 1;

    const int tid  = threadIdx.x;
    const int lane = tid & 63;
    const int w    = tid >> 6;
    const int lo   = lane & 15;
    const int hi   = lane >> 4;

    __shared__ unsigned short Ks[KB][HD + 8];    // stride 272B == 4 banks mod 32
    __shared__ unsigned short Vt[HD][KB + 16];   // stride 160B == 8 banks mod 32
    __shared__ unsigned short Ps[QB][KB + 8];

    short8 qf[4];
    {
        int row = q0 + w * 16 + lo;
        const unsigned short* qp = Qb + ((size_t)b * T + row) * HD + hi * 8;
#pragma unroll
        for (int ks = 0; ks < 4; ++ks) qf[ks] = *(const short8*)(qp + ks * 32);
    }

    float mrow[4], lrow[4];
    f32x4 o[8];
#pragma unroll
    for (int r = 0; r < 4; ++r) { mrow[r] = -1e30f; lrow[r] = 0.0f; }
#pragma unroll
    for (int n = 0; n < 8; ++n) o[n] = (f32x4)0.0f;

    const float scale2 = 0.022097086912079608f * 1.4426950408889634f;
    const int qrow_base = q0 + w * 16 + hi * 4;

    for (int t = t0; t < t1; ++t) {
        const int kv0 = t * KB;
#pragma unroll
        for (int it = 0; it < 4; ++it) {
            int c = tid + it * 256;
            int row = c >> 4, c8 = (c & 15) * 8;
            *(short8*)&Ks[row][c8] =
                *(const short8*)(Kb + ((size_t)b * T + kv0 + row) * HD + c8);
        }
#pragma unroll
        for (int it = 0; it < 4; ++it) {
            int c = tid + it * 256;
            int row = c >> 3, c8 = (c & 7) * 8;
            *(short8*)&Vt[row][c8] =
                *(const short8*)(VtG + (size_t)(b * HD + row) * T + kv0 + c8);
        }
        __syncthreads();

        f32x4 sa[4];
#pragma unroll
        for (int j = 0; j < 4; ++j) sa[j] = (f32x4)0.0f;
#pragma unroll
        for (int ks = 0; ks < 4; ++ks) {
#pragma unroll
            for (int j = 0; j < 4; ++j) {
                short8 bf = *(const short8*)&Ks[j * 16 + lo][ks * 32 + hi * 8];
                sa[j] = __builtin_amdgcn_mfma_f32_16x16x32_bf16(qf[ks], bf, sa[j], 0, 0, 0);
            }
        }

        const bool diag = (t == qt);
        float alpha[4];
#pragma unroll
        for (int r = 0; r < 4; ++r) {
            const int qrow = qrow_base + r;
            float rm = -1e30f;
#pragma unroll
            for (int j = 0; j < 4; ++j) {
                float v = sa[j][r] * scale2;
                if (diag) {
                    int kv = kv0 + j * 16 + lo;
                    v = (kv <= qrow) ? v : -1e30f;
                }
                sa[j][r] = v;
                rm = fmaxf(rm, v);
            }
            rm = fmaxf(rm, __shfl_xor(rm, 1));
            rm = fmaxf(rm, __shfl_xor(rm, 2));
            rm = fmaxf(rm, __shfl_xor(rm, 4));
            rm = fmaxf(rm, __shfl_xor(rm, 8));
            float mn = fmaxf(mrow[r], rm);
            alpha[r] = exp2f(mrow[r] - mn);
            mrow[r] = mn;
            float ls = 0.0f;
#pragma unroll
            for (int j = 0; j < 4; ++j) {
                float p = exp2f(sa[j][r] - mn);
                sa[j][r] = p;
                ls += p;
            }
            ls += __shfl_xor(ls, 1);
            ls += __shfl_xor(ls, 2);
            ls += __shfl_xor(ls, 4);
            ls += __shfl_xor(ls, 8);
            lrow[r] = lrow[r] * alpha[r] + ls;
        }
#pragma unroll
        for (int n = 0; n < 8; ++n)
#pragma unroll
            for (int r = 0; r < 4; ++r) o[n][r] *= alpha[r];

#pragma unroll
        for (int r = 0; r < 4; ++r)
#pragma unroll
            for (int j = 0; j < 4; ++j)
                Ps[w * 16 + hi * 4 + r][j * 16 + lo] = f2bf(sa[j][r]);
        __syncthreads();

#pragma unroll
        for (int ks = 0; ks < 2; ++ks) {
            short8 af = *(const short8*)&Ps[w * 16 + lo][ks * 32 + hi * 8];
#pragma unroll
            for (int n = 0; n < 8; ++n) {
                short8 bv = *(const short8*)&Vt[n * 16 + lo][ks * 32 + hi * 8];
                o[n] = __builtin_amdgcn_mfma_f32_16x16x32_bf16(af, bv, o[n], 0, 0, 0);
            }
        }
        __syncthreads();
    }

    if (nsplit == 1) {
#pragma unroll
        for (int n = 0; n < 8; ++n) {
            int h = n * 16 + lo;
#pragma unroll
            for (int r = 0; r < 4; ++r) {
                int row = qrow_base + r;
                out[((size_t)b * T + row) * HD + h] = o[n][r] / lrow[r];
            }
        }
    } else {
        const size_t slot = (size_t)(b * 32 + qt) * 4 + s;
        float* po = part_o + slot * (QB * HD);
#pragma unroll
        for (int n = 0; n < 8; ++n) {
            int h = n * 16 + lo;
#pragma unroll
            for (int r = 0; r < 4; ++r)
                po[(w * 16 + hi * 4 + r) * HD + h] = o[n][r];
        }
        if (lo == 0) {
            float* pm = part_ml + slot * (QB * 2);
#pragma unroll
            for (int r = 0; r < 4; ++r) {
                pm[(w * 16 + hi * 4 + r) * 2 + 0] = mrow[r];
                pm[(w * 16 + hi * 4 + r) * 2 + 1] = lrow[r];
            }
        }
    }
}

// ---------------------------------------------------------------------------
// Kernel 3: combine split partials (only q-tiles 8..31 have >1 split)
// ---------------------------------------------------------------------------
__global__ __launch_bounds__(256) void attn_combine(
    const float* __restrict__ part_o, const float* __restrict__ part_ml,
    float* __restrict__ out)
{
    const int qt = 8 + blockIdx.x;     // 8..31
    const int b  = blockIdx.y;
    const int ns = qt / 8 + 1;         // 2..4
    const int tid = threadIdx.x;
    const int row = tid >> 2;          // 0..63
    const int c0  = (tid & 3) * 32;
    const size_t slot0 = (size_t)(b * 32 + qt) * 4;

    float mi[4], li[4];
    float m = -1e30f;
#pragma unroll 4
    for (int i = 0; i < ns; ++i) {
        mi[i] = part_ml[(slot0 + i) * (QB * 2) + row * 2 + 0];
        li[i] = part_ml[(slot0 + i) * (QB * 2) + row * 2 + 1];
        m = fmaxf(m, mi[i]);
    }
    float L = 0.0f, f[4];
#pragma unroll 4
    for (int i = 0; i < ns; ++i) {
        f[i] = exp2f(mi[i] - m);
        L += li[i] * f[i];
    }
    const float inv = 1.0f / L;

    float4 acc[8];
#pragma unroll
    for (int k = 0; k < 8; ++k) acc[k] = make_float4(0.f, 0.f, 0.f, 0.f);
#pragma unroll 4
    for (int i = 0; i < ns; ++i) {
        const float4* src = (const float4*)(part_o + (slot0 + i) * (QB * HD) + row * HD + c0);
#pragma unroll
        for (int k = 0; k < 8; ++k) {
            float4 v = src[k];
            acc[k].x += f[i] * v.x; acc[k].y += f[i] * v.y;
            acc[k].z += f[i] * v.z; acc[k].w += f[i] * v.w;
        }
    }
    float4* dst = (float4*)(out + ((size_t)b * T + qt * QB + row) * HD + c0);
#pragma unroll
    for (int k = 0; k < 8; ++k) {
        float4 v = acc[k];
        dst[k] = make_float4(v.x * inv, v.y * inv, v.z * inv, v.w * inv);
    }
}

// ---------------------------------------------------------------------------
extern "C" void kernel_launch(void* const* d_in, const int* in_sizes, int n_in,
                              void* d_out, int out_size, void* d_ws, size_t ws_size,
                              hipStream_t stream)
{
    const float* x  = (const float*)d_in[0];
    const float* Wq = (const float*)d_in[1];
    const float* Wk = (const float*)d_in[2];
    const float* Wv = (const float*)d_in[3];
    float* out = (float*)d_out;

    // ws layout (bytes)
    const size_t off_Wb = 0;
    const size_t off_Q  = off_Wb + (size_t)NW * EMB * 2;        // 1.5 MB
    const size_t off_K  = off_Q  + (size_t)M * HD * 2;          // +4 MB
    const size_t off_V  = off_K  + (size_t)M * HD * 2;
    const size_t off_po = off_V  + (size_t)M * HD * 2;
    const size_t off_ml = off_po + (size_t)1024 * QB * HD * 4;  // 32 MB partials
    const size_t total  = off_ml + (size_t)1024 * QB * 2 * 4;

    char* ws = (char*)d_ws;
    unsigned short* Wb  = (unsigned short*)(ws + off_Wb);
    unsigned short* Qb  = (unsigned short*)(ws + off_Q);
    unsigned short* Kb  = (unsigned short*)(ws + off_K);
    unsigned short* VtG = (unsigned short*)(ws + off_V);
    float* part_o  = (float*)(ws + off_po);
    float* part_ml = (float*)(ws + off_ml);

    const int use_split = (ws_size >= total) ? 1 : 0;

    conv_w<<<dim3((NW * EMB) / (256 * 8)), 256, 0, stream>>>(Wq, Wk, Wv, Wb);
    qkv_proj<<<dim3(M / PBM), 512, 0, stream>>>(x, Wb, Qb, Kb, VtG);
    attn_fwd<<<dim3(use_split ? 80 : 32, B), 256, 0, stream>>>(
        Qb, Kb, VtG, out, part_o, part_ml, use_split);
    if (use_split) {
        attn_combine<<<dim3(24, B), 256, 0, stream>>>(part_o, part_ml, out);
        // --- diagnostics (after all real work; scratch region of part_o) ---
        diag_stage<<<dim3(M / PBM), 512, 0, stream>>>(x, Wb, part_o);
        diag_compute<<<dim3(M / PBM), 512, 0, stream>>>(x, Wb, part_o + (1 << 20));
    }
}

// Round 10
// 168.958 us; speedup vs baseline: 1.6785x; 1.6785x over previous
//
#include <hip/hip_runtime.h>
#include <hip/hip_bf16.h>
#include <stdint.h>

// Problem constants
constexpr int B    = 8;
constexpr int T    = 2048;
constexpr int EMB  = 2048;
constexpr int HD   = 128;
constexpr int M    = B * T;        // 16384 rows for projection GEMM
constexpr int NW   = 3 * HD;       // 384 fused output cols (Q|K|V)

typedef __attribute__((ext_vector_type(8))) short short8;
typedef __attribute__((ext_vector_type(4))) float f32x4;

__device__ inline unsigned short f2bf(float f) {
    union { float f; unsigned int u; } v; v.f = f;
    unsigned int x = v.u;
    unsigned int r = (x + 0x7FFFu + ((x >> 16) & 1u)) >> 16;   // RNE
    return (unsigned short)r;
}

__device__ inline unsigned int cvt_pk_bf16(float a, float b) {
    unsigned int r;
    asm volatile("v_cvt_pk_bf16_f32 %0, %1, %2" : "=v"(r) : "v"(a), "v"(b));
    return r;   // lo = bf16(a), hi = bf16(b)
}

// ---------------------------------------------------------------------------
// Kernel 0: convert Wq|Wk|Wv fp32 -> bf16 into Wb[384][2048]
// ---------------------------------------------------------------------------
__global__ __launch_bounds__(256) void conv_w(
    const float* __restrict__ Wq, const float* __restrict__ Wk, const float* __restrict__ Wv,
    unsigned short* __restrict__ Wb)
{
    int base = (blockIdx.x * 256 + threadIdx.x) * 8;   // < 384*2048
    int row = base >> 11, col = base & 2047;
    const float* src;
    if (row < 128)      src = Wq + (size_t)row * EMB + col;
    else if (row < 256) src = Wk + (size_t)(row - 128) * EMB + col;
    else                src = Wv + (size_t)(row - 256) * EMB + col;
    float4 a = *(const float4*)src;
    float4 b = *(const float4*)(src + 4);
    short8 sv;
    sv[0] = f2bf(a.x); sv[1] = f2bf(a.y); sv[2] = f2bf(a.z); sv[3] = f2bf(a.w);
    sv[4] = f2bf(b.x); sv[5] = f2bf(b.y); sv[6] = f2bf(b.z); sv[7] = f2bf(b.w);
    *(short8*)(Wb + base) = sv;
}

// ---------------------------------------------------------------------------
// Kernel 1: fused QKV projection — BARRIER-FREE main loop.
// R9 ablation: LDS-staging W each K-step costs 40us alone (drain-bound).
// New flow: x-slice 32x2048 bf16 (128.5 KB) staged in LDS ONCE (1 barrier);
// W streamed L2->REGISTERS as B-operand, prefetched 1 step ahead; no barriers
// or waitcnt in the 32-step loop. Grid 512 = M/32, 512 thr = 8 waves; wave w
// owns cols [w*48, w*48+48): per K-step (64) 4 ds_read_b128 + 6 global 16B
// loads + 12 MFMA. Each W element read once per block (768 MB L2 total).
// Q,K written [M][128] bf16; V written TRANSPOSED [B][128][T] bf16.
// ---------------------------------------------------------------------------
constexpr int PBM  = 32;
constexpr int PBK  = 64;
constexpr int PNT  = EMB / PBK;   // 32
constexpr int XPAD = 8;           // shorts; row stride 4112B -> optimal 8-phase b128

__global__ __launch_bounds__(512) void qkv_proj(
    const float* __restrict__ x, const unsigned short* __restrict__ Wb,
    unsigned short* __restrict__ Qb, unsigned short* __restrict__ Kb,
    unsigned short* __restrict__ VtG)
{
    __shared__ unsigned short Xs[PBM][EMB + XPAD];   // 131.5 KB

    const int m0   = blockIdx.x * PBM;
    const int tid  = threadIdx.x;
    const int lane = tid & 63;
    const int w    = tid >> 6;           // 0..7
    const int lo   = lane & 15;
    const int hi   = lane >> 4;

    // ---- prologue: stage x tile 32x2048 fp32 -> bf16 into LDS (once) ----
#pragma unroll
    for (int it = 0; it < 16; ++it) {
        int c   = it * 512 + tid;        // 8192 chunks of 8 floats
        int row = c >> 8;
        int c8  = (c & 255) * 8;
        const float* src = x + (size_t)(m0 + row) * EMB + c8;
        float4 u = *(const float4*)src;
        float4 v = *(const float4*)(src + 4);
        uint4 p;
        p.x = cvt_pk_bf16(u.x, u.y);  p.y = cvt_pk_bf16(u.z, u.w);
        p.z = cvt_pk_bf16(v.x, v.y);  p.w = cvt_pk_bf16(v.z, v.w);
        *(uint4*)&Xs[row][c8] = p;
    }
    __syncthreads();   // the ONLY barrier

    f32x4 acc[2][3];
#pragma unroll
    for (int i = 0; i < 2; ++i)
#pragma unroll
        for (int j = 0; j < 3; ++j) acc[i][j] = (f32x4)0.0f;

    // per-lane W base addresses (B-operand rows = output cols)
    const unsigned short* wbase[3];
#pragma unroll
    for (int j = 0; j < 3; ++j)
        wbase[j] = Wb + (size_t)(w * 48 + j * 16 + lo) * EMB + hi * 8;

    // preload step 0 W fragments
    short8 bfc[2][3];
#pragma unroll
    for (int kk = 0; kk < 2; ++kk)
#pragma unroll
        for (int j = 0; j < 3; ++j)
            bfc[kk][j] = *(const short8*)(wbase[j] + kk * 32);

#pragma unroll 1
    for (int t = 0; t < PNT; ++t) {
        const int k0 = t * PBK;
        const int kn = (t + 1 < PNT ? t + 1 : t) * PBK;   // branchless clamp
        short8 bfn[2][3];
#pragma unroll
        for (int kk = 0; kk < 2; ++kk)
#pragma unroll
            for (int j = 0; j < 3; ++j)
                bfn[kk][j] = *(const short8*)(wbase[j] + kn + kk * 32);   // prefetch t+1
#pragma unroll
        for (int kk = 0; kk < 2; ++kk) {
            short8 af[2];
#pragma unroll
            for (int i = 0; i < 2; ++i)
                af[i] = *(const short8*)&Xs[i * 16 + lo][k0 + kk * 32 + hi * 8];
#pragma unroll
            for (int i = 0; i < 2; ++i)
#pragma unroll
                for (int j = 0; j < 3; ++j)
                    acc[i][j] = __builtin_amdgcn_mfma_f32_16x16x32_bf16(af[i], bfc[kk][j], acc[i][j], 0, 0, 0);
        }
#pragma unroll
        for (int kk = 0; kk < 2; ++kk)
#pragma unroll
            for (int j = 0; j < 3; ++j)
                bfc[kk][j] = bfn[kk][j];
    }

    // epilogue. C layout: row = hi*4+r, col = lo. cw = 16-col chunk = w*3+j.
    const int b = m0 >> 11;
#pragma unroll
    for (int i = 0; i < 2; ++i) {
        int mrow0 = m0 + i * 16 + hi * 4;
#pragma unroll
        for (int j = 0; j < 3; ++j) {
            int cw = w * 3 + j;
            int colbase = cw * 16 + lo;
            if (cw < 8) {                      // Q
#pragma unroll
                for (int r = 0; r < 4; ++r)
                    Qb[(size_t)(mrow0 + r) * HD + colbase] = f2bf(acc[i][j][r]);
            } else if (cw < 16) {              // K
#pragma unroll
                for (int r = 0; r < 4; ++r)
                    Kb[(size_t)(mrow0 + r) * HD + (colbase - 128)] = f2bf(acc[i][j][r]);
            } else {                           // V -> transposed [B][HD][T]
                int h = colbase - 256;
                int tloc = mrow0 - b * T;
                ushort4 pv;
                pv.x = f2bf(acc[i][j][0]); pv.y = f2bf(acc[i][j][1]);
                pv.z = f2bf(acc[i][j][2]); pv.w = f2bf(acc[i][j][3]);
                *(ushort4*)(VtG + ((size_t)(b * HD + h)) * T + tloc) = pv;
            }
        }
    }
}

// ---------------------------------------------------------------------------
// Kernel 2: causal flash attention with KV-split (flash-decoding style).
// ---------------------------------------------------------------------------
constexpr int QB = 64;
constexpr int KB = 64;
constexpr int STILES = 8;   // kv tiles per split block

__global__ __launch_bounds__(256) void attn_fwd(
    const unsigned short* __restrict__ Qb,
    const unsigned short* __restrict__ Kb,
    const unsigned short* __restrict__ VtG,
    float* __restrict__ out,
    float* __restrict__ part_o, float* __restrict__ part_ml,
    int use_split)
{
    const int b  = blockIdx.y;
    int bx = blockIdx.x;
    int qt, s, nsplit;
    if (use_split) {
        if (bx < 8)       { qt = bx;               s = 0; }
        else if (bx < 24) { qt = 8  + (bx - 8) / 2;  s = (bx - 8) & 1; }
        else if (bx < 48) { qt = 16 + (bx - 24) / 3; s = (bx - 24) % 3; }
        else              { qt = 24 + (bx - 48) / 4; s = (bx - 48) & 3; }
        nsplit = qt / 8 + 1;
    } else {
        qt = bx; s = 0; nsplit = 1;
    }
    const int q0 = qt * QB;
    int t0 = s * STILES;
    int t1 = t0 + STILES; if (t1 > qt + 1) t1 = qt + 1;

    const int tid  = threadIdx.x;
    const int lane = tid & 63;
    const int w    = tid >> 6;
    const int lo   = lane & 15;
    const int hi   = lane >> 4;

    __shared__ unsigned short Ks[KB][HD + 8];    // stride 272B == 4 banks mod 32
    __shared__ unsigned short Vt[HD][KB + 16];   // stride 160B == 8 banks mod 32
    __shared__ unsigned short Ps[QB][KB + 8];

    short8 qf[4];
    {
        int row = q0 + w * 16 + lo;
        const unsigned short* qp = Qb + ((size_t)b * T + row) * HD + hi * 8;
#pragma unroll
        for (int ks = 0; ks < 4; ++ks) qf[ks] = *(const short8*)(qp + ks * 32);
    }

    float mrow[4], lrow[4];
    f32x4 o[8];
#pragma unroll
    for (int r = 0; r < 4; ++r) { mrow[r] = -1e30f; lrow[r] = 0.0f; }
#pragma unroll
    for (int n = 0; n < 8; ++n) o[n] = (f32x4)0.0f;

    const float scale2 = 0.022097086912079608f * 1.4426950408889634f;
    const int qrow_base = q0 + w * 16 + hi * 4;

    for (int t = t0; t < t1; ++t) {
        const int kv0 = t * KB;
#pragma unroll
        for (int it = 0; it < 4; ++it) {
            int c = tid + it * 256;
            int row = c >> 4, c8 = (c & 15) * 8;
            *(short8*)&Ks[row][c8] =
                *(const short8*)(Kb + ((size_t)b * T + kv0 + row) * HD + c8);
        }
#pragma unroll
        for (int it = 0; it < 4; ++it) {
            int c = tid + it * 256;
            int row = c >> 3, c8 = (c & 7) * 8;
            *(short8*)&Vt[row][c8] =
                *(const short8*)(VtG + (size_t)(b * HD + row) * T + kv0 + c8);
        }
        __syncthreads();

        f32x4 sa[4];
#pragma unroll
        for (int j = 0; j < 4; ++j) sa[j] = (f32x4)0.0f;
#pragma unroll
        for (int ks = 0; ks < 4; ++ks) {
#pragma unroll
            for (int j = 0; j < 4; ++j) {
                short8 bf = *(const short8*)&Ks[j * 16 + lo][ks * 32 + hi * 8];
                sa[j] = __builtin_amdgcn_mfma_f32_16x16x32_bf16(qf[ks], bf, sa[j], 0, 0, 0);
            }
        }

        const bool diag = (t == qt);
        float alpha[4];
#pragma unroll
        for (int r = 0; r < 4; ++r) {
            const int qrow = qrow_base + r;
            float rm = -1e30f;
#pragma unroll
            for (int j = 0; j < 4; ++j) {
                float v = sa[j][r] * scale2;
                if (diag) {
                    int kv = kv0 + j * 16 + lo;
                    v = (kv <= qrow) ? v : -1e30f;
                }
                sa[j][r] = v;
                rm = fmaxf(rm, v);
            }
            rm = fmaxf(rm, __shfl_xor(rm, 1));
            rm = fmaxf(rm, __shfl_xor(rm, 2));
            rm = fmaxf(rm, __shfl_xor(rm, 4));
            rm = fmaxf(rm, __shfl_xor(rm, 8));
            float mn = fmaxf(mrow[r], rm);
            alpha[r] = exp2f(mrow[r] - mn);
            mrow[r] = mn;
            float ls = 0.0f;
#pragma unroll
            for (int j = 0; j < 4; ++j) {
                float p = exp2f(sa[j][r] - mn);
                sa[j][r] = p;
                ls += p;
            }
            ls += __shfl_xor(ls, 1);
            ls += __shfl_xor(ls, 2);
            ls += __shfl_xor(ls, 4);
            ls += __shfl_xor(ls, 8);
            lrow[r] = lrow[r] * alpha[r] + ls;
        }
#pragma unroll
        for (int n = 0; n < 8; ++n)
#pragma unroll
            for (int r = 0; r < 4; ++r) o[n][r] *= alpha[r];

#pragma unroll
        for (int r = 0; r < 4; ++r)
#pragma unroll
            for (int j = 0; j < 4; ++j)
                Ps[w * 16 + hi * 4 + r][j * 16 + lo] = f2bf(sa[j][r]);
        __syncthreads();

#pragma unroll
        for (int ks = 0; ks < 2; ++ks) {
            short8 af = *(const short8*)&Ps[w * 16 + lo][ks * 32 + hi * 8];
#pragma unroll
            for (int n = 0; n < 8; ++n) {
                short8 bv = *(const short8*)&Vt[n * 16 + lo][ks * 32 + hi * 8];
                o[n] = __builtin_amdgcn_mfma_f32_16x16x32_bf16(af, bv, o[n], 0, 0, 0);
            }
        }
        __syncthreads();
    }

    if (nsplit == 1) {
#pragma unroll
        for (int n = 0; n < 8; ++n) {
            int h = n * 16 + lo;
#pragma unroll
            for (int r = 0; r < 4; ++r) {
                int row = qrow_base + r;
                out[((size_t)b * T + row) * HD + h] = o[n][r] / lrow[r];
            }
        }
    } else {
        const size_t slot = (size_t)(b * 32 + qt) * 4 + s;
        float* po = part_o + slot * (QB * HD);
#pragma unroll
        for (int n = 0; n < 8; ++n) {
            int h = n * 16 + lo;
#pragma unroll
            for (int r = 0; r < 4; ++r)
                po[(w * 16 + hi * 4 + r) * HD + h] = o[n][r];
        }
        if (lo == 0) {
            float* pm = part_ml + slot * (QB * 2);
#pragma unroll
            for (int r = 0; r < 4; ++r) {
                pm[(w * 16 + hi * 4 + r) * 2 + 0] = mrow[r];
                pm[(w * 16 + hi * 4 + r) * 2 + 1] = lrow[r];
            }
        }
    }
}

// ---------------------------------------------------------------------------
// Kernel 3: combine split partials (only q-tiles 8..31 have >1 split)
// ---------------------------------------------------------------------------
__global__ __launch_bounds__(256) void attn_combine(
    const float* __restrict__ part_o, const float* __restrict__ part_ml,
    float* __restrict__ out)
{
    const int qt = 8 + blockIdx.x;     // 8..31
    const int b  = blockIdx.y;
    const int ns = qt / 8 + 1;         // 2..4
    const int tid = threadIdx.x;
    const int row = tid >> 2;          // 0..63
    const int c0  = (tid & 3) * 32;
    const size_t slot0 = (size_t)(b * 32 + qt) * 4;

    float mi[4], li[4];
    float m = -1e30f;
#pragma unroll 4
    for (int i = 0; i < ns; ++i) {
        mi[i] = part_ml[(slot0 + i) * (QB * 2) + row * 2 + 0];
        li[i] = part_ml[(slot0 + i) * (QB * 2) + row * 2 + 1];
        m = fmaxf(m, mi[i]);
    }
    float L = 0.0f, f[4];
#pragma unroll 4
    for (int i = 0; i < ns; ++i) {
        f[i] = exp2f(mi[i] - m);
        L += li[i] * f[i];
    }
    const float inv = 1.0f / L;

    float4 acc[8];
#pragma unroll
    for (int k = 0; k < 8; ++k) acc[k] = make_float4(0.f, 0.f, 0.f, 0.f);
#pragma unroll 4
    for (int i = 0; i < ns; ++i) {
        const float4* src = (const float4*)(part_o + (slot0 + i) * (QB * HD) + row * HD + c0);
#pragma unroll
        for (int k = 0; k < 8; ++k) {
            float4 v = src[k];
            acc[k].x += f[i] * v.x; acc[k].y += f[i] * v.y;
            acc[k].z += f[i] * v.z; acc[k].w += f[i] * v.w;
        }
    }
    float4* dst = (float4*)(out + ((size_t)b * T + qt * QB + row) * HD + c0);
#pragma unroll
    for (int k = 0; k < 8; ++k) {
        float4 v = acc[k];
        dst[k] = make_float4(v.x * inv, v.y * inv, v.z * inv, v.w * inv);
    }
}

// ---------------------------------------------------------------------------
extern "C" void kernel_launch(void* const* d_in, const int* in_sizes, int n_in,
                              void* d_out, int out_size, void* d_ws, size_t ws_size,
                              hipStream_t stream)
{
    const float* x  = (const float*)d_in[0];
    const float* Wq = (const float*)d_in[1];
    const float* Wk = (const float*)d_in[2];
    const float* Wv = (const float*)d_in[3];
    float* out = (float*)d_out;

    // ws layout (bytes)
    const size_t off_Wb = 0;
    const size_t off_Q  = off_Wb + (size_t)NW * EMB * 2;        // 1.5 MB
    const size_t off_K  = off_Q  + (size_t)M * HD * 2;          // +4 MB
    const size_t off_V  = off_K  + (size_t)M * HD * 2;
    const size_t off_po = off_V  + (size_t)M * HD * 2;
    const size_t off_ml = off_po + (size_t)1024 * QB * HD * 4;  // 32 MB partials
    const size_t total  = off_ml + (size_t)1024 * QB * 2 * 4;

    char* ws = (char*)d_ws;
    unsigned short* Wb  = (unsigned short*)(ws + off_Wb);
    unsigned short* Qb  = (unsigned short*)(ws + off_Q);
    unsigned short* Kb  = (unsigned short*)(ws + off_K);
    unsigned short* VtG = (unsigned short*)(ws + off_V);
    float* part_o  = (float*)(ws + off_po);
    float* part_ml = (float*)(ws + off_ml);

    const int use_split = (ws_size >= total) ? 1 : 0;

    conv_w<<<dim3((NW * EMB) / (256 * 8)), 256, 0, stream>>>(Wq, Wk, Wv, Wb);
    qkv_proj<<<dim3(M / PBM), 512, 0, stream>>>(x, Wb, Qb, Kb, VtG);
    attn_fwd<<<dim3(use_split ? 80 : 32, B), 256, 0, stream>>>(
        Qb, Kb, VtG, out, part_o, part_ml, use_split);
    if (use_split)
        attn_combine<<<dim3(24, B), 256, 0, stream>>>(part_o, part_ml, out);
}

// Round 11
// 111.941 us; speedup vs baseline: 2.5335x; 1.5094x over previous
//
#include <hip/hip_runtime.h>
#include <hip/hip_bf16.h>
#include <stdint.h>

// Problem constants
constexpr int B    = 8;
constexpr int T    = 2048;
constexpr int EMB  = 2048;
constexpr int HD   = 128;
constexpr int M    = B * T;        // 16384 rows for projection GEMM
constexpr int NW   = 3 * HD;       // 384 fused output cols (Q|K|V)

typedef __attribute__((ext_vector_type(8))) short short8;
typedef __attribute__((ext_vector_type(4))) float f32x4;

__device__ inline unsigned short f2bf(float f) {
    union { float f; unsigned int u; } v; v.f = f;
    unsigned int x = v.u;
    unsigned int r = (x + 0x7FFFu + ((x >> 16) & 1u)) >> 16;   // RNE
    return (unsigned short)r;
}

__device__ inline unsigned int cvt_pk_bf16(float a, float b) {
    unsigned int r;
    asm volatile("v_cvt_pk_bf16_f32 %0, %1, %2" : "=v"(r) : "v"(a), "v"(b));
    return r;   // lo = bf16(a), hi = bf16(b)
}

// ---------------------------------------------------------------------------
// Kernel 0: convert Wq|Wk|Wv fp32 -> bf16 into Wb[384][2048]
// ---------------------------------------------------------------------------
__global__ __launch_bounds__(256) void conv_w(
    const float* __restrict__ Wq, const float* __restrict__ Wk, const float* __restrict__ Wv,
    unsigned short* __restrict__ Wb)
{
    int base = (blockIdx.x * 256 + threadIdx.x) * 8;   // < 384*2048
    int row = base >> 11, col = base & 2047;
    const float* src;
    if (row < 128)      src = Wq + (size_t)row * EMB + col;
    else if (row < 256) src = Wk + (size_t)(row - 128) * EMB + col;
    else                src = Wv + (size_t)(row - 256) * EMB + col;
    float4 a = *(const float4*)src;
    float4 b = *(const float4*)(src + 4);
    short8 sv;
    sv[0] = f2bf(a.x); sv[1] = f2bf(a.y); sv[2] = f2bf(a.z); sv[3] = f2bf(a.w);
    sv[4] = f2bf(b.x); sv[5] = f2bf(b.y); sv[6] = f2bf(b.z); sv[7] = f2bf(b.w);
    *(short8*)(Wb + base) = sv;
}

// ---------------------------------------------------------------------------
// Kernel 1: fused QKV projection — counted-vmcnt 2-deep pipeline (T3+T4).
// Geometry = R8 (best-understood): 64(M) x 384(N full) x BK=64, 32 tiles,
// grid 256 (1 block/CU), 512 thr = 8 waves; wave w = cols [w*48, w*48+48),
// all 64 rows: 4x3 16x16 frags, 24 MFMA + 14 ds_read_b128 per tile.
// Per tile: exactly 8 VMEM ops {2 A-reg loads, 6 B global_load_lds}.
// KEY FIX vs R2-R8: raw s_barrier (no implicit vmcnt-0 drain) + counted
// s_waitcnt vmcnt(8) that waits only the PREVIOUS tile's group — issued a
// full compute phase earlier. Loads stay in flight across barriers (T4).
// 2-unrolled loop: even/odd named A-register sets (rule 20), static bufs.
// Q,K written [M][128] bf16; V written TRANSPOSED [B][128][T] bf16.
// ---------------------------------------------------------------------------
constexpr int PBM = 64;
constexpr int PBK = 64;
constexpr int PNT = EMB / PBK;   // 32

__global__ __launch_bounds__(512) void qkv_proj(
    const float* __restrict__ x, const unsigned short* __restrict__ Wb,
    unsigned short* __restrict__ Qb, unsigned short* __restrict__ Kb,
    unsigned short* __restrict__ VtG)
{
    __shared__ unsigned short Ab[2][PBM * PBK];   // 2 x 8 KB
    __shared__ unsigned short Bb[2][NW * PBK];    // 2 x 48 KB  (112 KB total)

    const int m0   = blockIdx.x * PBM;
    const int tid  = threadIdx.x;
    const int lane = tid & 63;
    const int w    = tid >> 6;           // 0..7
    const int lo   = lane & 15;
    const int hi   = lane >> 4;

    // A staging coords: thread -> (row 0..63, 8-float seg 0..7)
    const int ar = tid >> 3;
    const int as = tid & 7;
    const float* asrc = x + (size_t)(m0 + ar) * EMB + as * 8;

    f32x4 acc[4][3];
#pragma unroll
    for (int i = 0; i < 4; ++i)
#pragma unroll
        for (int j = 0; j < 3; ++j) acc[i][j] = (f32x4)0.0f;

    auto stageB = [&](int k0, int buf) {
        // 384x64 bf16 = 48 KB = 3072 x 16B chunks = 6 insts x 512 lanes.
        // linear dest; source seg pre-swizzled: lseg = pseg ^ (row&7)
#pragma unroll
        for (int it = 0; it < 6; ++it) {
            int c = it * 512 + tid;
            int row = c >> 3;
            int lseg = (c & 7) ^ (row & 7);
            __builtin_amdgcn_global_load_lds(
                (const __attribute__((address_space(1))) unsigned int*)
                    (Wb + (size_t)row * EMB + k0 + lseg * 8),
                (__attribute__((address_space(3))) unsigned int*)
                    ((char*)&Bb[buf][0] + (it * 512 + w * 64) * 16),
                16, 0, 0);
        }
    };
    auto writeA = [&](int buf, float4 A0, float4 A1) {
        uint4 p;
        p.x = cvt_pk_bf16(A0.x, A0.y);
        p.y = cvt_pk_bf16(A0.z, A0.w);
        p.z = cvt_pk_bf16(A1.x, A1.y);
        p.w = cvt_pk_bf16(A1.z, A1.w);
        int ps = as ^ (ar & 7);
        *(uint4*)&Ab[buf][ar * PBK + ps * 8] = p;
    };
    auto compute = [&](int buf) {
#pragma unroll
        for (int kk = 0; kk < 2; ++kk) {
            short8 af[4], bf[3];
            const int cseg = kk * 4 + hi;
#pragma unroll
            for (int i = 0; i < 4; ++i) {
                int R = i * 16 + lo;
                af[i] = *(const short8*)&Ab[buf][R * PBK + (cseg ^ (R & 7)) * 8];
            }
#pragma unroll
            for (int j = 0; j < 3; ++j) {
                int n = w * 48 + j * 16 + lo;
                bf[j] = *(const short8*)&Bb[buf][n * PBK + (cseg ^ (n & 7)) * 8];
            }
#pragma unroll
            for (int i = 0; i < 4; ++i)
#pragma unroll
                for (int j = 0; j < 3; ++j)
                    acc[i][j] = __builtin_amdgcn_mfma_f32_16x16x32_bf16(af[i], bf[j], acc[i][j], 0, 0, 0);
        }
    };

    float4 a0e, a1e, a0o, a1o;   // even/odd tile A registers (named: rule 20)

    // ---- prologue: issue tiles 0 (even) and 1 (odd); group order pinned ----
    a0e = *(const float4*)(asrc + 0);
    a1e = *(const float4*)(asrc + 4);
    __builtin_amdgcn_sched_barrier(0);
    stageB(0, 0);
    __builtin_amdgcn_sched_barrier(0);
    a0o = *(const float4*)(asrc + PBK);
    a1o = *(const float4*)(asrc + PBK + 4);
    __builtin_amdgcn_sched_barrier(0);
    stageB(PBK, 1);
    __builtin_amdgcn_sched_barrier(0);
    asm volatile("s_waitcnt vmcnt(8)" ::: "memory");   // tile 0 landed; tile 1 in flight
    __builtin_amdgcn_sched_barrier(0);
    writeA(0, a0e, a1e);
    asm volatile("s_waitcnt lgkmcnt(0)" ::: "memory");
    __builtin_amdgcn_sched_barrier(0);
    __builtin_amdgcn_s_barrier();

#pragma unroll 1
    for (int tt = 0; tt < PNT / 2; ++tt) {
        const int t = tt * 2;
        // ================= even tile t (buf 0, regs e) =================
        compute(0);
        __builtin_amdgcn_s_barrier();              // all waves done reading buf 0
        if (t + 2 < PNT) {
            a0e = *(const float4*)(asrc + (t + 2) * PBK);
            a1e = *(const float4*)(asrc + (t + 2) * PBK + 4);
            __builtin_amdgcn_sched_barrier(0);
            stageB((t + 2) * PBK, 0);
            __builtin_amdgcn_sched_barrier(0);
            asm volatile("s_waitcnt vmcnt(8)" ::: "memory");   // tile t+1 landed
        } else {
            asm volatile("s_waitcnt vmcnt(0)" ::: "memory");   // tail drain
        }
        __builtin_amdgcn_sched_barrier(0);
        writeA(1, a0o, a1o);                       // tile t+1's A
        asm volatile("s_waitcnt lgkmcnt(0)" ::: "memory");
        __builtin_amdgcn_sched_barrier(0);
        __builtin_amdgcn_s_barrier();
        // ================= odd tile t+1 (buf 1, regs o) ================
        compute(1);
        if (t + 1 == PNT - 1) break;
        __builtin_amdgcn_s_barrier();
        if (t + 3 < PNT) {
            a0o = *(const float4*)(asrc + (t + 3) * PBK);
            a1o = *(const float4*)(asrc + (t + 3) * PBK + 4);
            __builtin_amdgcn_sched_barrier(0);
            stageB((t + 3) * PBK, 1);
            __builtin_amdgcn_sched_barrier(0);
            asm volatile("s_waitcnt vmcnt(8)" ::: "memory");   // tile t+2 landed
        } else {
            asm volatile("s_waitcnt vmcnt(0)" ::: "memory");
        }
        __builtin_amdgcn_sched_barrier(0);
        writeA(0, a0e, a1e);                       // tile t+2's A
        asm volatile("s_waitcnt lgkmcnt(0)" ::: "memory");
        __builtin_amdgcn_sched_barrier(0);
        __builtin_amdgcn_s_barrier();
    }

    // epilogue. C layout: row = hi*4+r, col = lo. cw = 16-col chunk 0..23.
    const int b = m0 >> 11;
#pragma unroll
    for (int i = 0; i < 4; ++i) {
        int mrow0 = m0 + i * 16 + hi * 4;
#pragma unroll
        for (int j = 0; j < 3; ++j) {
            int cw = w * 3 + j;
            int colbase = cw * 16 + lo;
            if (cw < 8) {                      // Q
#pragma unroll
                for (int r = 0; r < 4; ++r)
                    Qb[(size_t)(mrow0 + r) * HD + colbase] = f2bf(acc[i][j][r]);
            } else if (cw < 16) {              // K
#pragma unroll
                for (int r = 0; r < 4; ++r)
                    Kb[(size_t)(mrow0 + r) * HD + (colbase - 128)] = f2bf(acc[i][j][r]);
            } else {                           // V -> transposed [B][HD][T]
                int h = colbase - 256;
                int tloc = mrow0 - b * T;
                ushort4 pv;
                pv.x = f2bf(acc[i][j][0]); pv.y = f2bf(acc[i][j][1]);
                pv.z = f2bf(acc[i][j][2]); pv.w = f2bf(acc[i][j][3]);
                *(ushort4*)(VtG + ((size_t)(b * HD + h)) * T + tloc) = pv;
            }
        }
    }
}

// ---------------------------------------------------------------------------
// Kernel 2: causal flash attention with KV-split (flash-decoding style).
// ---------------------------------------------------------------------------
constexpr int QB = 64;
constexpr int KB = 64;
constexpr int STILES = 8;   // kv tiles per split block

__global__ __launch_bounds__(256) void attn_fwd(
    const unsigned short* __restrict__ Qb,
    const unsigned short* __restrict__ Kb,
    const unsigned short* __restrict__ VtG,
    float* __restrict__ out,
    float* __restrict__ part_o, float* __restrict__ part_ml,
    int use_split)
{
    const int b  = blockIdx.y;
    int bx = blockIdx.x;
    int qt, s, nsplit;
    if (use_split) {
        if (bx < 8)       { qt = bx;               s = 0; }
        else if (bx < 24) { qt = 8  + (bx - 8) / 2;  s = (bx - 8) & 1; }
        else if (bx < 48) { qt = 16 + (bx - 24) / 3; s = (bx - 24) % 3; }
        else              { qt = 24 + (bx - 48) / 4; s = (bx - 48) & 3; }
        nsplit = qt / 8 + 1;
    } else {
        qt = bx; s = 0; nsplit = 1;
    }
    const int q0 = qt * QB;
    int t0 = s * STILES;
    int t1 = t0 + STILES; if (t1 > qt + 1) t1 = qt + 1;

    const int tid  = threadIdx.x;
    const int lane = tid & 63;
    const int w    = tid >> 6;
    const int lo   = lane & 15;
    const int hi   = lane >> 4;

    __shared__ unsigned short Ks[KB][HD + 8];    // stride 272B == 4 banks mod 32
    __shared__ unsigned short Vt[HD][KB + 16];   // stride 160B == 8 banks mod 32
    __shared__ unsigned short Ps[QB][KB + 8];

    short8 qf[4];
    {
        int row = q0 + w * 16 + lo;
        const unsigned short* qp = Qb + ((size_t)b * T + row) * HD + hi * 8;
#pragma unroll
        for (int ks = 0; ks < 4; ++ks) qf[ks] = *(const short8*)(qp + ks * 32);
    }

    float mrow[4], lrow[4];
    f32x4 o[8];
#pragma unroll
    for (int r = 0; r < 4; ++r) { mrow[r] = -1e30f; lrow[r] = 0.0f; }
#pragma unroll
    for (int n = 0; n < 8; ++n) o[n] = (f32x4)0.0f;

    const float scale2 = 0.022097086912079608f * 1.4426950408889634f;
    const int qrow_base = q0 + w * 16 + hi * 4;

    for (int t = t0; t < t1; ++t) {
        const int kv0 = t * KB;
#pragma unroll
        for (int it = 0; it < 4; ++it) {
            int c = tid + it * 256;
            int row = c >> 4, c8 = (c & 15) * 8;
            *(short8*)&Ks[row][c8] =
                *(const short8*)(Kb + ((size_t)b * T + kv0 + row) * HD + c8);
        }
#pragma unroll
        for (int it = 0; it < 4; ++it) {
            int c = tid + it * 256;
            int row = c >> 3, c8 = (c & 7) * 8;
            *(short8*)&Vt[row][c8] =
                *(const short8*)(VtG + (size_t)(b * HD + row) * T + kv0 + c8);
        }
        __syncthreads();

        f32x4 sa[4];
#pragma unroll
        for (int j = 0; j < 4; ++j) sa[j] = (f32x4)0.0f;
#pragma unroll
        for (int ks = 0; ks < 4; ++ks) {
#pragma unroll
            for (int j = 0; j < 4; ++j) {
                short8 bf = *(const short8*)&Ks[j * 16 + lo][ks * 32 + hi * 8];
                sa[j] = __builtin_amdgcn_mfma_f32_16x16x32_bf16(qf[ks], bf, sa[j], 0, 0, 0);
            }
        }

        const bool diag = (t == qt);
        float alpha[4];
#pragma unroll
        for (int r = 0; r < 4; ++r) {
            const int qrow = qrow_base + r;
            float rm = -1e30f;
#pragma unroll
            for (int j = 0; j < 4; ++j) {
                float v = sa[j][r] * scale2;
                if (diag) {
                    int kv = kv0 + j * 16 + lo;
                    v = (kv <= qrow) ? v : -1e30f;
                }
                sa[j][r] = v;
                rm = fmaxf(rm, v);
            }
            rm = fmaxf(rm, __shfl_xor(rm, 1));
            rm = fmaxf(rm, __shfl_xor(rm, 2));
            rm = fmaxf(rm, __shfl_xor(rm, 4));
            rm = fmaxf(rm, __shfl_xor(rm, 8));
            float mn = fmaxf(mrow[r], rm);
            alpha[r] = exp2f(mrow[r] - mn);
            mrow[r] = mn;
            float ls = 0.0f;
#pragma unroll
            for (int j = 0; j < 4; ++j) {
                float p = exp2f(sa[j][r] - mn);
                sa[j][r] = p;
                ls += p;
            }
            ls += __shfl_xor(ls, 1);
            ls += __shfl_xor(ls, 2);
            ls += __shfl_xor(ls, 4);
            ls += __shfl_xor(ls, 8);
            lrow[r] = lrow[r] * alpha[r] + ls;
        }
#pragma unroll
        for (int n = 0; n < 8; ++n)
#pragma unroll
            for (int r = 0; r < 4; ++r) o[n][r] *= alpha[r];

#pragma unroll
        for (int r = 0; r < 4; ++r)
#pragma unroll
            for (int j = 0; j < 4; ++j)
                Ps[w * 16 + hi * 4 + r][j * 16 + lo] = f2bf(sa[j][r]);
        __syncthreads();

#pragma unroll
        for (int ks = 0; ks < 2; ++ks) {
            short8 af = *(const short8*)&Ps[w * 16 + lo][ks * 32 + hi * 8];
#pragma unroll
            for (int n = 0; n < 8; ++n) {
                short8 bv = *(const short8*)&Vt[n * 16 + lo][ks * 32 + hi * 8];
                o[n] = __builtin_amdgcn_mfma_f32_16x16x32_bf16(af, bv, o[n], 0, 0, 0);
            }
        }
        __syncthreads();
    }

    if (nsplit == 1) {
#pragma unroll
        for (int n = 0; n < 8; ++n) {
            int h = n * 16 + lo;
#pragma unroll
            for (int r = 0; r < 4; ++r) {
                int row = qrow_base + r;
                out[((size_t)b * T + row) * HD + h] = o[n][r] / lrow[r];
            }
        }
    } else {
        const size_t slot = (size_t)(b * 32 + qt) * 4 + s;
        float* po = part_o + slot * (QB * HD);
#pragma unroll
        for (int n = 0; n < 8; ++n) {
            int h = n * 16 + lo;
#pragma unroll
            for (int r = 0; r < 4; ++r)
                po[(w * 16 + hi * 4 + r) * HD + h] = o[n][r];
        }
        if (lo == 0) {
            float* pm = part_ml + slot * (QB * 2);
#pragma unroll
            for (int r = 0; r < 4; ++r) {
                pm[(w * 16 + hi * 4 + r) * 2 + 0] = mrow[r];
                pm[(w * 16 + hi * 4 + r) * 2 + 1] = lrow[r];
            }
        }
    }
}

// ---------------------------------------------------------------------------
// Kernel 3: combine split partials (only q-tiles 8..31 have >1 split)
// ---------------------------------------------------------------------------
__global__ __launch_bounds__(256) void attn_combine(
    const float* __restrict__ part_o, const float* __restrict__ part_ml,
    float* __restrict__ out)
{
    const int qt = 8 + blockIdx.x;     // 8..31
    const int b  = blockIdx.y;
    const int ns = qt / 8 + 1;         // 2..4
    const int tid = threadIdx.x;
    const int row = tid >> 2;          // 0..63
    const int c0  = (tid & 3) * 32;
    const size_t slot0 = (size_t)(b * 32 + qt) * 4;

    float mi[4], li[4];
    float m = -1e30f;
#pragma unroll 4
    for (int i = 0; i < ns; ++i) {
        mi[i] = part_ml[(slot0 + i) * (QB * 2) + row * 2 + 0];
        li[i] = part_ml[(slot0 + i) * (QB * 2) + row * 2 + 1];
        m = fmaxf(m, mi[i]);
    }
    float L = 0.0f, f[4];
#pragma unroll 4
    for (int i = 0; i < ns; ++i) {
        f[i] = exp2f(mi[i] - m);
        L += li[i] * f[i];
    }
    const float inv = 1.0f / L;

    float4 acc[8];
#pragma unroll
    for (int k = 0; k < 8; ++k) acc[k] = make_float4(0.f, 0.f, 0.f, 0.f);
#pragma unroll 4
    for (int i = 0; i < ns; ++i) {
        const float4* src = (const float4*)(part_o + (slot0 + i) * (QB * HD) + row * HD + c0);
#pragma unroll
        for (int k = 0; k < 8; ++k) {
            float4 v = src[k];
            acc[k].x += f[i] * v.x; acc[k].y += f[i] * v.y;
            acc[k].z += f[i] * v.z; acc[k].w += f[i] * v.w;
        }
    }
    float4* dst = (float4*)(out + ((size_t)b * T + qt * QB + row) * HD + c0);
#pragma unroll
    for (int k = 0; k < 8; ++k) {
        float4 v = acc[k];
        dst[k] = make_float4(v.x * inv, v.y * inv, v.z * inv, v.w * inv);
    }
}

// ---------------------------------------------------------------------------
extern "C" void kernel_launch(void* const* d_in, const int* in_sizes, int n_in,
                              void* d_out, int out_size, void* d_ws, size_t ws_size,
                              hipStream_t stream)
{
    const float* x  = (const float*)d_in[0];
    const float* Wq = (const float*)d_in[1];
    const float* Wk = (const float*)d_in[2];
    const float* Wv = (const float*)d_in[3];
    float* out = (float*)d_out;

    // ws layout (bytes)
    const size_t off_Wb = 0;
    const size_t off_Q  = off_Wb + (size_t)NW * EMB * 2;        // 1.5 MB
    const size_t off_K  = off_Q  + (size_t)M * HD * 2;          // +4 MB
    const size_t off_V  = off_K  + (size_t)M * HD * 2;
    const size_t off_po = off_V  + (size_t)M * HD * 2;
    const size_t off_ml = off_po + (size_t)1024 * QB * HD * 4;  // 32 MB partials
    const size_t total  = off_ml + (size_t)1024 * QB * 2 * 4;

    char* ws = (char*)d_ws;
    unsigned short* Wb  = (unsigned short*)(ws + off_Wb);
    unsigned short* Qb  = (unsigned short*)(ws + off_Q);
    unsigned short* Kb  = (unsigned short*)(ws + off_K);
    unsigned short* VtG = (unsigned short*)(ws + off_V);
    float* part_o  = (float*)(ws + off_po);
    float* part_ml = (float*)(ws + off_ml);

    const int use_split = (ws_size >= total) ? 1 : 0;

    conv_w<<<dim3((NW * EMB) / (256 * 8)), 256, 0, stream>>>(Wq, Wk, Wv, Wb);
    qkv_proj<<<dim3(M / PBM), 512, 0, stream>>>(x, Wb, Qb, Kb, VtG);
    attn_fwd<<<dim3(use_split ? 80 : 32, B), 256, 0, stream>>>(
        Qb, Kb, VtG, out, part_o, part_ml, use_split);
    if (use_split)
        attn_combine<<<dim3(24, B), 256, 0, stream>>>(part_o, part_ml, out);
}

// Round 12
// 102.578 us; speedup vs baseline: 2.7648x; 1.0913x over previous
//
#include <hip/hip_runtime.h>
#include <hip/hip_bf16.h>
#include <stdint.h>

// Problem constants
constexpr int B    = 8;
constexpr int T    = 2048;
constexpr int EMB  = 2048;
constexpr int HD   = 128;
constexpr int M    = B * T;        // 16384 rows for projection GEMM
constexpr int NW   = 3 * HD;       // 384 fused output cols (Q|K|V)

typedef __attribute__((ext_vector_type(8))) short short8;
typedef __attribute__((ext_vector_type(4))) float f32x4;

__device__ inline unsigned short f2bf(float f) {
    union { float f; unsigned int u; } v; v.f = f;
    unsigned int x = v.u;
    unsigned int r = (x + 0x7FFFu + ((x >> 16) & 1u)) >> 16;   // RNE
    return (unsigned short)r;
}

__device__ inline unsigned int cvt_pk_bf16(float a, float b) {
    unsigned int r;
    asm volatile("v_cvt_pk_bf16_f32 %0, %1, %2" : "=v"(r) : "v"(a), "v"(b));
    return r;   // lo = bf16(a), hi = bf16(b)
}

// ---------------------------------------------------------------------------
// Kernel 0: convert Wq|Wk|Wv fp32 -> bf16 into Wb[384][2048]
// ---------------------------------------------------------------------------
__global__ __launch_bounds__(256) void conv_w(
    const float* __restrict__ Wq, const float* __restrict__ Wk, const float* __restrict__ Wv,
    unsigned short* __restrict__ Wb)
{
    int base = (blockIdx.x * 256 + threadIdx.x) * 8;   // < 384*2048
    int row = base >> 11, col = base & 2047;
    const float* src;
    if (row < 128)      src = Wq + (size_t)row * EMB + col;
    else if (row < 256) src = Wk + (size_t)(row - 128) * EMB + col;
    else                src = Wv + (size_t)(row - 256) * EMB + col;
    float4 a = *(const float4*)src;
    float4 b = *(const float4*)(src + 4);
    short8 sv;
    sv[0] = f2bf(a.x); sv[1] = f2bf(a.y); sv[2] = f2bf(a.z); sv[3] = f2bf(a.w);
    sv[4] = f2bf(b.x); sv[5] = f2bf(b.y); sv[6] = f2bf(b.z); sv[7] = f2bf(b.w);
    *(short8*)(Wb + base) = sv;
}

// ---------------------------------------------------------------------------
// Kernel 1: fused QKV projection — REG-STAGED B (T14), fast ds_write path.
// R9/R11 diagnosis: global_load_lds DMA writes LDS at ~20 B/cyc/CU; with
// 1 block/CU there is nothing to overlap the 48 KB/step DMA with -> stage
// (~3000cy) + compute (~1300cy) serialize. Fix: B loaded to REGISTERS
// (coalesced, issued before compute = full phase to cover latency), then
// burst into LDS via ds_write_b128 (~256 B/cyc, ~250cy). One barrier/step.
// Geometry: 64(M) x 384(N full) x BK=64, 32 tiles, grid 256 (1 block/CU),
// 512 thr = 8 waves; wave w = cols [w*48,+48), 4x3 frags, 24 MFMA/tile.
// LDS swizzle: XOR on ds_write addr + same XOR on read (verified R7-R11).
// Q,K written [M][128] bf16; V written TRANSPOSED [B][128][T] bf16.
// ---------------------------------------------------------------------------
constexpr int PBM = 64;
constexpr int PBK = 64;
constexpr int PNT = EMB / PBK;   // 32

__global__ __launch_bounds__(512) void qkv_proj(
    const float* __restrict__ x, const unsigned short* __restrict__ Wb,
    unsigned short* __restrict__ Qb, unsigned short* __restrict__ Kb,
    unsigned short* __restrict__ VtG)
{
    __shared__ unsigned short Ab[2][PBM * PBK];   // 2 x 8 KB
    __shared__ unsigned short Bb[2][NW * PBK];    // 2 x 48 KB  (112 KB total)

    const int m0   = blockIdx.x * PBM;
    const int tid  = threadIdx.x;
    const int lane = tid & 63;
    const int w    = tid >> 6;           // 0..7
    const int lo   = lane & 15;
    const int hi   = lane >> 4;

    // A staging coords: thread -> (row 0..63, 8-float seg 0..7)
    const int ar = tid >> 3;
    const int as = tid & 7;
    const float* asrc = x + (size_t)(m0 + ar) * EMB + as * 8;

    f32x4 acc[4][3];
#pragma unroll
    for (int i = 0; i < 4; ++i)
#pragma unroll
        for (int j = 0; j < 3; ++j) acc[i][j] = (f32x4)0.0f;

    short8 breg[6];
    float4 a0, a1;

    auto loadTile = [&](int k0) {
        // B: 384x64 bf16 = 3072 x 16B chunks = 6 x 512 lanes, LINEAR global
#pragma unroll
        for (int it = 0; it < 6; ++it) {
            int c = it * 512 + tid;
            int row = c >> 3, seg = c & 7;
            breg[it] = *(const short8*)(Wb + (size_t)row * EMB + k0 + seg * 8);
        }
        a0 = *(const float4*)(asrc + k0);
        a1 = *(const float4*)(asrc + k0 + 4);
    };
    auto writeTile = [&](int buf) {
#pragma unroll
        for (int it = 0; it < 6; ++it) {
            int c = it * 512 + tid;
            int row = c >> 3, seg = c & 7;
            *(short8*)&Bb[buf][row * PBK + ((seg ^ (row & 7))) * 8] = breg[it];
        }
        uint4 p;
        p.x = cvt_pk_bf16(a0.x, a0.y);
        p.y = cvt_pk_bf16(a0.z, a0.w);
        p.z = cvt_pk_bf16(a1.x, a1.y);
        p.w = cvt_pk_bf16(a1.z, a1.w);
        *(uint4*)&Ab[buf][ar * PBK + (as ^ (ar & 7)) * 8] = p;
    };
    auto compute = [&](int buf) {
#pragma unroll
        for (int kk = 0; kk < 2; ++kk) {
            short8 af[4], bf[3];
            const int cseg = kk * 4 + hi;
#pragma unroll
            for (int i = 0; i < 4; ++i) {
                int R = i * 16 + lo;
                af[i] = *(const short8*)&Ab[buf][R * PBK + (cseg ^ (R & 7)) * 8];
            }
#pragma unroll
            for (int j = 0; j < 3; ++j) {
                int n = w * 48 + j * 16 + lo;
                bf[j] = *(const short8*)&Bb[buf][n * PBK + (cseg ^ (n & 7)) * 8];
            }
#pragma unroll
            for (int i = 0; i < 4; ++i)
#pragma unroll
                for (int j = 0; j < 3; ++j)
                    acc[i][j] = __builtin_amdgcn_mfma_f32_16x16x32_bf16(af[i], bf[j], acc[i][j], 0, 0, 0);
        }
    };

    // prologue: tile 0 through regs into buf 0
    loadTile(0);
    writeTile(0);
    __syncthreads();

#pragma unroll 1
    for (int t = 0; t < PNT; ++t) {
        const int buf = t & 1;
        if (t + 1 < PNT) {
            loadTile((t + 1) * PBK);              // 8 VMEM issued FIRST
            __builtin_amdgcn_sched_barrier(0);    // pin: loads before compute
        }
        compute(buf);
        if (t + 1 < PNT) {
            __builtin_amdgcn_sched_barrier(0);    // pin: writes after compute
            writeTile(buf ^ 1);                   // waits only own 8 loads
            __syncthreads();
        }
    }

    // epilogue. C layout: row = hi*4+r, col = lo. cw = 16-col chunk 0..23.
    const int b = m0 >> 11;
#pragma unroll
    for (int i = 0; i < 4; ++i) {
        int mrow0 = m0 + i * 16 + hi * 4;
#pragma unroll
        for (int j = 0; j < 3; ++j) {
            int cw = w * 3 + j;
            int colbase = cw * 16 + lo;
            if (cw < 8) {                      // Q
#pragma unroll
                for (int r = 0; r < 4; ++r)
                    Qb[(size_t)(mrow0 + r) * HD + colbase] = f2bf(acc[i][j][r]);
            } else if (cw < 16) {              // K
#pragma unroll
                for (int r = 0; r < 4; ++r)
                    Kb[(size_t)(mrow0 + r) * HD + (colbase - 128)] = f2bf(acc[i][j][r]);
            } else {                           // V -> transposed [B][HD][T]
                int h = colbase - 256;
                int tloc = mrow0 - b * T;
                ushort4 pv;
                pv.x = f2bf(acc[i][j][0]); pv.y = f2bf(acc[i][j][1]);
                pv.z = f2bf(acc[i][j][2]); pv.w = f2bf(acc[i][j][3]);
                *(ushort4*)(VtG + ((size_t)(b * HD + h)) * T + tloc) = pv;
            }
        }
    }
}

// ---------------------------------------------------------------------------
// Kernel 2: causal flash attention with KV-split (flash-decoding style).
// ---------------------------------------------------------------------------
constexpr int QB = 64;
constexpr int KB = 64;
constexpr int STILES = 8;   // kv tiles per split block

__global__ __launch_bounds__(256) void attn_fwd(
    const unsigned short* __restrict__ Qb,
    const unsigned short* __restrict__ Kb,
    const unsigned short* __restrict__ VtG,
    float* __restrict__ out,
    float* __restrict__ part_o, float* __restrict__ part_ml,
    int use_split)
{
    const int b  = blockIdx.y;
    int bx = blockIdx.x;
    int qt, s, nsplit;
    if (use_split) {
        if (bx < 8)       { qt = bx;               s = 0; }
        else if (bx < 24) { qt = 8  + (bx - 8) / 2;  s = (bx - 8) & 1; }
        else if (bx < 48) { qt = 16 + (bx - 24) / 3; s = (bx - 24) % 3; }
        else              { qt = 24 + (bx - 48) / 4; s = (bx - 48) & 3; }
        nsplit = qt / 8 + 1;
    } else {
        qt = bx; s = 0; nsplit = 1;
    }
    const int q0 = qt * QB;
    int t0 = s * STILES;
    int t1 = t0 + STILES; if (t1 > qt + 1) t1 = qt + 1;

    const int tid  = threadIdx.x;
    const int lane = tid & 63;
    const int w    = tid >> 6;
    const int lo   = lane & 15;
    const int hi   = lane >> 4;

    __shared__ unsigned short Ks[KB][HD + 8];    // stride 272B == 4 banks mod 32
    __shared__ unsigned short Vt[HD][KB + 16];   // stride 160B == 8 banks mod 32
    __shared__ unsigned short Ps[QB][KB + 8];

    short8 qf[4];
    {
        int row = q0 + w * 16 + lo;
        const unsigned short* qp = Qb + ((size_t)b * T + row) * HD + hi * 8;
#pragma unroll
        for (int ks = 0; ks < 4; ++ks) qf[ks] = *(const short8*)(qp + ks * 32);
    }

    float mrow[4], lrow[4];
    f32x4 o[8];
#pragma unroll
    for (int r = 0; r < 4; ++r) { mrow[r] = -1e30f; lrow[r] = 0.0f; }
#pragma unroll
    for (int n = 0; n < 8; ++n) o[n] = (f32x4)0.0f;

    const float scale2 = 0.022097086912079608f * 1.4426950408889634f;
    const int qrow_base = q0 + w * 16 + hi * 4;

    for (int t = t0; t < t1; ++t) {
        const int kv0 = t * KB;
#pragma unroll
        for (int it = 0; it < 4; ++it) {
            int c = tid + it * 256;
            int row = c >> 4, c8 = (c & 15) * 8;
            *(short8*)&Ks[row][c8] =
                *(const short8*)(Kb + ((size_t)b * T + kv0 + row) * HD + c8);
        }
#pragma unroll
        for (int it = 0; it < 4; ++it) {
            int c = tid + it * 256;
            int row = c >> 3, c8 = (c & 7) * 8;
            *(short8*)&Vt[row][c8] =
                *(const short8*)(VtG + (size_t)(b * HD + row) * T + kv0 + c8);
        }
        __syncthreads();

        f32x4 sa[4];
#pragma unroll
        for (int j = 0; j < 4; ++j) sa[j] = (f32x4)0.0f;
#pragma unroll
        for (int ks = 0; ks < 4; ++ks) {
#pragma unroll
            for (int j = 0; j < 4; ++j) {
                short8 bf = *(const short8*)&Ks[j * 16 + lo][ks * 32 + hi * 8];
                sa[j] = __builtin_amdgcn_mfma_f32_16x16x32_bf16(qf[ks], bf, sa[j], 0, 0, 0);
            }
        }

        const bool diag = (t == qt);
        float alpha[4];
#pragma unroll
        for (int r = 0; r < 4; ++r) {
            const int qrow = qrow_base + r;
            float rm = -1e30f;
#pragma unroll
            for (int j = 0; j < 4; ++j) {
                float v = sa[j][r] * scale2;
                if (diag) {
                    int kv = kv0 + j * 16 + lo;
                    v = (kv <= qrow) ? v : -1e30f;
                }
                sa[j][r] = v;
                rm = fmaxf(rm, v);
            }
            rm = fmaxf(rm, __shfl_xor(rm, 1));
            rm = fmaxf(rm, __shfl_xor(rm, 2));
            rm = fmaxf(rm, __shfl_xor(rm, 4));
            rm = fmaxf(rm, __shfl_xor(rm, 8));
            float mn = fmaxf(mrow[r], rm);
            alpha[r] = exp2f(mrow[r] - mn);
            mrow[r] = mn;
            float ls = 0.0f;
#pragma unroll
            for (int j = 0; j < 4; ++j) {
                float p = exp2f(sa[j][r] - mn);
                sa[j][r] = p;
                ls += p;
            }
            ls += __shfl_xor(ls, 1);
            ls += __shfl_xor(ls, 2);
            ls += __shfl_xor(ls, 4);
            ls += __shfl_xor(ls, 8);
            lrow[r] = lrow[r] * alpha[r] + ls;
        }
#pragma unroll
        for (int n = 0; n < 8; ++n)
#pragma unroll
            for (int r = 0; r < 4; ++r) o[n][r] *= alpha[r];

#pragma unroll
        for (int r = 0; r < 4; ++r)
#pragma unroll
            for (int j = 0; j < 4; ++j)
                Ps[w * 16 + hi * 4 + r][j * 16 + lo] = f2bf(sa[j][r]);
        __syncthreads();

#pragma unroll
        for (int ks = 0; ks < 2; ++ks) {
            short8 af = *(const short8*)&Ps[w * 16 + lo][ks * 32 + hi * 8];
#pragma unroll
            for (int n = 0; n < 8; ++n) {
                short8 bv = *(const short8*)&Vt[n * 16 + lo][ks * 32 + hi * 8];
                o[n] = __builtin_amdgcn_mfma_f32_16x16x32_bf16(af, bv, o[n], 0, 0, 0);
            }
        }
        __syncthreads();
    }

    if (nsplit == 1) {
#pragma unroll
        for (int n = 0; n < 8; ++n) {
            int h = n * 16 + lo;
#pragma unroll
            for (int r = 0; r < 4; ++r) {
                int row = qrow_base + r;
                out[((size_t)b * T + row) * HD + h] = o[n][r] / lrow[r];
            }
        }
    } else {
        const size_t slot = (size_t)(b * 32 + qt) * 4 + s;
        float* po = part_o + slot * (QB * HD);
#pragma unroll
        for (int n = 0; n < 8; ++n) {
            int h = n * 16 + lo;
#pragma unroll
            for (int r = 0; r < 4; ++r)
                po[(w * 16 + hi * 4 + r) * HD + h] = o[n][r];
        }
        if (lo == 0) {
            float* pm = part_ml + slot * (QB * 2);
#pragma unroll
            for (int r = 0; r < 4; ++r) {
                pm[(w * 16 + hi * 4 + r) * 2 + 0] = mrow[r];
                pm[(w * 16 + hi * 4 + r) * 2 + 1] = lrow[r];
            }
        }
    }
}

// ---------------------------------------------------------------------------
// Kernel 3: combine split partials (only q-tiles 8..31 have >1 split)
// ---------------------------------------------------------------------------
__global__ __launch_bounds__(256) void attn_combine(
    const float* __restrict__ part_o, const float* __restrict__ part_ml,
    float* __restrict__ out)
{
    const int qt = 8 + blockIdx.x;     // 8..31
    const int b  = blockIdx.y;
    const int ns = qt / 8 + 1;         // 2..4
    const int tid = threadIdx.x;
    const int row = tid >> 2;          // 0..63
    const int c0  = (tid & 3) * 32;
    const size_t slot0 = (size_t)(b * 32 + qt) * 4;

    float mi[4], li[4];
    float m = -1e30f;
#pragma unroll 4
    for (int i = 0; i < ns; ++i) {
        mi[i] = part_ml[(slot0 + i) * (QB * 2) + row * 2 + 0];
        li[i] = part_ml[(slot0 + i) * (QB * 2) + row * 2 + 1];
        m = fmaxf(m, mi[i]);
    }
    float L = 0.0f, f[4];
#pragma unroll 4
    for (int i = 0; i < ns; ++i) {
        f[i] = exp2f(mi[i] - m);
        L += li[i] * f[i];
    }
    const float inv = 1.0f / L;

    float4 acc[8];
#pragma unroll
    for (int k = 0; k < 8; ++k) acc[k] = make_float4(0.f, 0.f, 0.f, 0.f);
#pragma unroll 4
    for (int i = 0; i < ns; ++i) {
        const float4* src = (const float4*)(part_o + (slot0 + i) * (QB * HD) + row * HD + c0);
#pragma unroll
        for (int k = 0; k < 8; ++k) {
            float4 v = src[k];
            acc[k].x += f[i] * v.x; acc[k].y += f[i] * v.y;
            acc[k].z += f[i] * v.z; acc[k].w += f[i] * v.w;
        }
    }
    float4* dst = (float4*)(out + ((size_t)b * T + qt * QB + row) * HD + c0);
#pragma unroll
    for (int k = 0; k < 8; ++k) {
        float4 v = acc[k];
        dst[k] = make_float4(v.x * inv, v.y * inv, v.z * inv, v.w * inv);
    }
}

// ---------------------------------------------------------------------------
extern "C" void kernel_launch(void* const* d_in, const int* in_sizes, int n_in,
                              void* d_out, int out_size, void* d_ws, size_t ws_size,
                              hipStream_t stream)
{
    const float* x  = (const float*)d_in[0];
    const float* Wq = (const float*)d_in[1];
    const float* Wk = (const float*)d_in[2];
    const float* Wv = (const float*)d_in[3];
    float* out = (float*)d_out;

    // ws layout (bytes)
    const size_t off_Wb = 0;
    const size_t off_Q  = off_Wb + (size_t)NW * EMB * 2;        // 1.5 MB
    const size_t off_K  = off_Q  + (size_t)M * HD * 2;          // +4 MB
    const size_t off_V  = off_K  + (size_t)M * HD * 2;
    const size_t off_po = off_V  + (size_t)M * HD * 2;
    const size_t off_ml = off_po + (size_t)1024 * QB * HD * 4;  // 32 MB partials
    const size_t total  = off_ml + (size_t)1024 * QB * 2 * 4;

    char* ws = (char*)d_ws;
    unsigned short* Wb  = (unsigned short*)(ws + off_Wb);
    unsigned short* Qb  = (unsigned short*)(ws + off_Q);
    unsigned short* Kb  = (unsigned short*)(ws + off_K);
    unsigned short* VtG = (unsigned short*)(ws + off_V);
    float* part_o  = (float*)(ws + off_po);
    float* part_ml = (float*)(ws + off_ml);

    const int use_split = (ws_size >= total) ? 1 : 0;

    conv_w<<<dim3((NW * EMB) / (256 * 8)), 256, 0, stream>>>(Wq, Wk, Wv, Wb);
    qkv_proj<<<dim3(M / PBM), 512, 0, stream>>>(x, Wb, Qb, Kb, VtG);
    attn_fwd<<<dim3(use_split ? 80 : 32, B), 256, 0, stream>>>(
        Qb, Kb, VtG, out, part_o, part_ml, use_split);
    if (use_split)
        attn_combine<<<dim3(24, B), 256, 0, stream>>>(part_o, part_ml, out);
}

// Round 13
// 101.269 us; speedup vs baseline: 2.8005x; 1.0129x over previous
//
#include <hip/hip_runtime.h>
#include <hip/hip_bf16.h>
#include <stdint.h>

// Problem constants
constexpr int B    = 8;
constexpr int T    = 2048;
constexpr int EMB  = 2048;
constexpr int HD   = 128;
constexpr int M    = B * T;        // 16384 rows for projection GEMM
constexpr int NW   = 3 * HD;       // 384 fused output cols (Q|K|V)

typedef __attribute__((ext_vector_type(8))) short short8;
typedef __attribute__((ext_vector_type(4))) float f32x4;

__device__ inline unsigned short f2bf(float f) {
    union { float f; unsigned int u; } v; v.f = f;
    unsigned int x = v.u;
    unsigned int r = (x + 0x7FFFu + ((x >> 16) & 1u)) >> 16;   // RNE
    return (unsigned short)r;
}

__device__ inline unsigned int cvt_pk_bf16(float a, float b) {
    unsigned int r;
    asm volatile("v_cvt_pk_bf16_f32 %0, %1, %2" : "=v"(r) : "v"(a), "v"(b));
    return r;   // lo = bf16(a), hi = bf16(b)
}

// ---------------------------------------------------------------------------
// Kernel 0: convert Wq|Wk|Wv fp32 -> bf16 into Wb[384][2048]
// ---------------------------------------------------------------------------
__global__ __launch_bounds__(256) void conv_w(
    const float* __restrict__ Wq, const float* __restrict__ Wk, const float* __restrict__ Wv,
    unsigned short* __restrict__ Wb)
{
    int base = (blockIdx.x * 256 + threadIdx.x) * 8;   // < 384*2048
    int row = base >> 11, col = base & 2047;
    const float* src;
    if (row < 128)      src = Wq + (size_t)row * EMB + col;
    else if (row < 256) src = Wk + (size_t)(row - 128) * EMB + col;
    else                src = Wv + (size_t)(row - 256) * EMB + col;
    float4 a = *(const float4*)src;
    float4 b = *(const float4*)(src + 4);
    short8 sv;
    sv[0] = f2bf(a.x); sv[1] = f2bf(a.y); sv[2] = f2bf(a.z); sv[3] = f2bf(a.w);
    sv[4] = f2bf(b.x); sv[5] = f2bf(b.y); sv[6] = f2bf(b.z); sv[7] = f2bf(b.w);
    *(short8*)(Wb + base) = sv;
}

// ---------------------------------------------------------------------------
// Kernel 1: fused QKV projection — R12 loop, 2-blocks/CU residency (m114).
// R12 post-mortem: all 1-block/CU variants pinned at ~78us because barrier-
// locked waves have no cross-phase partner to hide stage latency/LDS bursts.
// Change ONLY residency: BN=192 (2-way N-split), BM=64 -> grid 512 = exactly
// 2 balanced blocks/CU (LDS 64 KB each). Same-XCD twin mapping: both N-halves
// of an M-tile on one XCD, concurrent -> x re-read is L2-local (fixes R3's
// HBM blowup). 256 thr = 4 waves; wave = 64x48 = 4x3 frags, 24 MFMA/step.
// B reg-staged linear loads + XOR ds_write; A reg-staged + cvt_pk (R12).
// Q,K written [M][128] bf16; V written TRANSPOSED [B][128][T] bf16.
// ---------------------------------------------------------------------------
constexpr int PBM = 64;
constexpr int PBN = 192;
constexpr int PBK = 64;
constexpr int PNT = EMB / PBK;   // 32

__global__ __launch_bounds__(256, 2) void qkv_proj(
    const float* __restrict__ x, const unsigned short* __restrict__ Wb,
    unsigned short* __restrict__ Qb, unsigned short* __restrict__ Kb,
    unsigned short* __restrict__ VtG)
{
    __shared__ unsigned short Ab[2][PBM * PBK];   // 2 x 8 KB
    __shared__ unsigned short Bb[2][PBN * PBK];   // 2 x 24 KB  (64 KB total)

    // same-XCD twin mapping: xcd = d&7 owns mt range [xcd*32, xcd*32+32)
    const int d   = blockIdx.x;          // 0..511
    const int xcd = d & 7;
    const int g   = d >> 3;              // 0..63
    const int mt  = xcd * 32 + (g >> 1); // 0..255
    const int ns  = g & 1;               // N-half
    const int m0  = mt * PBM;
    const int n0  = ns * PBN;

    const int tid  = threadIdx.x;
    const int lane = tid & 63;
    const int w    = tid >> 6;           // 0..3
    const int lo   = lane & 15;
    const int hi   = lane >> 4;

    // A staging coords: thread -> (row 0..63, 16-float span s0*8..s0*8+15)
    const int ar = tid >> 2;             // 0..63
    const int s0 = (tid & 3) * 2;        // first 8-float seg (0,2,4,6)
    const float* asrc = x + (size_t)(m0 + ar) * EMB + s0 * 8;

    f32x4 acc[4][3];
#pragma unroll
    for (int i = 0; i < 4; ++i)
#pragma unroll
        for (int j = 0; j < 3; ++j) acc[i][j] = (f32x4)0.0f;

    short8 breg[6];
    float4 a0, a1, a2, a3;

    auto loadTile = [&](int k0) {
        // B: 192x64 bf16 = 1536 x 16B chunks = 6 x 256 lanes, LINEAR global
#pragma unroll
        for (int it = 0; it < 6; ++it) {
            int c = it * 256 + tid;
            int row = c >> 3, seg = c & 7;
            breg[it] = *(const short8*)(Wb + (size_t)(n0 + row) * EMB + k0 + seg * 8);
        }
        a0 = *(const float4*)(asrc + k0);
        a1 = *(const float4*)(asrc + k0 + 4);
        a2 = *(const float4*)(asrc + k0 + 8);
        a3 = *(const float4*)(asrc + k0 + 12);
    };
    auto writeTile = [&](int buf) {
#pragma unroll
        for (int it = 0; it < 6; ++it) {
            int c = it * 256 + tid;
            int row = c >> 3, seg = c & 7;
            *(short8*)&Bb[buf][row * PBK + (seg ^ (row & 7)) * 8] = breg[it];
        }
        uint4 p0, p1;
        p0.x = cvt_pk_bf16(a0.x, a0.y);  p0.y = cvt_pk_bf16(a0.z, a0.w);
        p0.z = cvt_pk_bf16(a1.x, a1.y);  p0.w = cvt_pk_bf16(a1.z, a1.w);
        p1.x = cvt_pk_bf16(a2.x, a2.y);  p1.y = cvt_pk_bf16(a2.z, a2.w);
        p1.z = cvt_pk_bf16(a3.x, a3.y);  p1.w = cvt_pk_bf16(a3.z, a3.w);
        *(uint4*)&Ab[buf][ar * PBK + ((s0    ) ^ (ar & 7)) * 8] = p0;
        *(uint4*)&Ab[buf][ar * PBK + ((s0 + 1) ^ (ar & 7)) * 8] = p1;
    };
    auto compute = [&](int buf) {
#pragma unroll
        for (int kk = 0; kk < 2; ++kk) {
            short8 af[4], bf[3];
            const int cseg = kk * 4 + hi;
#pragma unroll
            for (int i = 0; i < 4; ++i) {
                int R = i * 16 + lo;
                af[i] = *(const short8*)&Ab[buf][R * PBK + (cseg ^ (R & 7)) * 8];
            }
#pragma unroll
            for (int j = 0; j < 3; ++j) {
                int n = w * 48 + j * 16 + lo;     // local col in 192
                bf[j] = *(const short8*)&Bb[buf][n * PBK + (cseg ^ (n & 7)) * 8];
            }
#pragma unroll
            for (int i = 0; i < 4; ++i)
#pragma unroll
                for (int j = 0; j < 3; ++j)
                    acc[i][j] = __builtin_amdgcn_mfma_f32_16x16x32_bf16(af[i], bf[j], acc[i][j], 0, 0, 0);
        }
    };

    // prologue: tile 0 through regs into buf 0
    loadTile(0);
    writeTile(0);
    __syncthreads();

#pragma unroll 1
    for (int t = 0; t < PNT; ++t) {
        const int buf = t & 1;
        if (t + 1 < PNT) {
            loadTile((t + 1) * PBK);              // 10 VMEM issued FIRST
            __builtin_amdgcn_sched_barrier(0);    // pin: loads before compute
        }
        compute(buf);
        if (t + 1 < PNT) {
            __builtin_amdgcn_sched_barrier(0);    // pin: writes after compute
            writeTile(buf ^ 1);                   // waits only own loads
            __syncthreads();
        }
    }

    // epilogue. C layout: row = hi*4+r, col = lo.
    const int b = m0 >> 11;
#pragma unroll
    for (int i = 0; i < 4; ++i) {
        int mrow0 = m0 + i * 16 + hi * 4;
#pragma unroll
        for (int j = 0; j < 3; ++j) {
            int colbase = n0 + w * 48 + j * 16 + lo;   // 0..383
            if (colbase < 128) {               // Q
#pragma unroll
                for (int r = 0; r < 4; ++r)
                    Qb[(size_t)(mrow0 + r) * HD + colbase] = f2bf(acc[i][j][r]);
            } else if (colbase < 256) {        // K
#pragma unroll
                for (int r = 0; r < 4; ++r)
                    Kb[(size_t)(mrow0 + r) * HD + (colbase - 128)] = f2bf(acc[i][j][r]);
            } else {                           // V -> transposed [B][HD][T]
                int h = colbase - 256;
                int tloc = mrow0 - b * T;
                ushort4 pv;
                pv.x = f2bf(acc[i][j][0]); pv.y = f2bf(acc[i][j][1]);
                pv.z = f2bf(acc[i][j][2]); pv.w = f2bf(acc[i][j][3]);
                *(ushort4*)(VtG + ((size_t)(b * HD + h)) * T + tloc) = pv;
            }
        }
    }
}

// ---------------------------------------------------------------------------
// Kernel 2: causal flash attention with KV-split (flash-decoding style).
// ---------------------------------------------------------------------------
constexpr int QB = 64;
constexpr int KB = 64;
constexpr int STILES = 8;   // kv tiles per split block

__global__ __launch_bounds__(256) void attn_fwd(
    const unsigned short* __restrict__ Qb,
    const unsigned short* __restrict__ Kb,
    const unsigned short* __restrict__ VtG,
    float* __restrict__ out,
    float* __restrict__ part_o, float* __restrict__ part_ml,
    int use_split)
{
    const int b  = blockIdx.y;
    int bx = blockIdx.x;
    int qt, s, nsplit;
    if (use_split) {
        if (bx < 8)       { qt = bx;               s = 0; }
        else if (bx < 24) { qt = 8  + (bx - 8) / 2;  s = (bx - 8) & 1; }
        else if (bx < 48) { qt = 16 + (bx - 24) / 3; s = (bx - 24) % 3; }
        else              { qt = 24 + (bx - 48) / 4; s = (bx - 48) & 3; }
        nsplit = qt / 8 + 1;
    } else {
        qt = bx; s = 0; nsplit = 1;
    }
    const int q0 = qt * QB;
    int t0 = s * STILES;
    int t1 = t0 + STILES; if (t1 > qt + 1) t1 = qt + 1;

    const int tid  = threadIdx.x;
    const int lane = tid & 63;
    const int w    = tid >> 6;
    const int lo   = lane & 15;
    const int hi   = lane >> 4;

    __shared__ unsigned short Ks[KB][HD + 8];    // stride 272B == 4 banks mod 32
    __shared__ unsigned short Vt[HD][KB + 16];   // stride 160B == 8 banks mod 32
    __shared__ unsigned short Ps[QB][KB + 8];

    short8 qf[4];
    {
        int row = q0 + w * 16 + lo;
        const unsigned short* qp = Qb + ((size_t)b * T + row) * HD + hi * 8;
#pragma unroll
        for (int ks = 0; ks < 4; ++ks) qf[ks] = *(const short8*)(qp + ks * 32);
    }

    float mrow[4], lrow[4];
    f32x4 o[8];
#pragma unroll
    for (int r = 0; r < 4; ++r) { mrow[r] = -1e30f; lrow[r] = 0.0f; }
#pragma unroll
    for (int n = 0; n < 8; ++n) o[n] = (f32x4)0.0f;

    const float scale2 = 0.022097086912079608f * 1.4426950408889634f;
    const int qrow_base = q0 + w * 16 + hi * 4;

    for (int t = t0; t < t1; ++t) {
        const int kv0 = t * KB;
#pragma unroll
        for (int it = 0; it < 4; ++it) {
            int c = tid + it * 256;
            int row = c >> 4, c8 = (c & 15) * 8;
            *(short8*)&Ks[row][c8] =
                *(const short8*)(Kb + ((size_t)b * T + kv0 + row) * HD + c8);
        }
#pragma unroll
        for (int it = 0; it < 4; ++it) {
            int c = tid + it * 256;
            int row = c >> 3, c8 = (c & 7) * 8;
            *(short8*)&Vt[row][c8] =
                *(const short8*)(VtG + (size_t)(b * HD + row) * T + kv0 + c8);
        }
        __syncthreads();

        f32x4 sa[4];
#pragma unroll
        for (int j = 0; j < 4; ++j) sa[j] = (f32x4)0.0f;
#pragma unroll
        for (int ks = 0; ks < 4; ++ks) {
#pragma unroll
            for (int j = 0; j < 4; ++j) {
                short8 bf = *(const short8*)&Ks[j * 16 + lo][ks * 32 + hi * 8];
                sa[j] = __builtin_amdgcn_mfma_f32_16x16x32_bf16(qf[ks], bf, sa[j], 0, 0, 0);
            }
        }

        const bool diag = (t == qt);
        float alpha[4];
#pragma unroll
        for (int r = 0; r < 4; ++r) {
            const int qrow = qrow_base + r;
            float rm = -1e30f;
#pragma unroll
            for (int j = 0; j < 4; ++j) {
                float v = sa[j][r] * scale2;
                if (diag) {
                    int kv = kv0 + j * 16 + lo;
                    v = (kv <= qrow) ? v : -1e30f;
                }
                sa[j][r] = v;
                rm = fmaxf(rm, v);
            }
            rm = fmaxf(rm, __shfl_xor(rm, 1));
            rm = fmaxf(rm, __shfl_xor(rm, 2));
            rm = fmaxf(rm, __shfl_xor(rm, 4));
            rm = fmaxf(rm, __shfl_xor(rm, 8));
            float mn = fmaxf(mrow[r], rm);
            alpha[r] = exp2f(mrow[r] - mn);
            mrow[r] = mn;
            float ls = 0.0f;
#pragma unroll
            for (int j = 0; j < 4; ++j) {
                float p = exp2f(sa[j][r] - mn);
                sa[j][r] = p;
                ls += p;
            }
            ls += __shfl_xor(ls, 1);
            ls += __shfl_xor(ls, 2);
            ls += __shfl_xor(ls, 4);
            ls += __shfl_xor(ls, 8);
            lrow[r] = lrow[r] * alpha[r] + ls;
        }
#pragma unroll
        for (int n = 0; n < 8; ++n)
#pragma unroll
            for (int r = 0; r < 4; ++r) o[n][r] *= alpha[r];

#pragma unroll
        for (int r = 0; r < 4; ++r)
#pragma unroll
            for (int j = 0; j < 4; ++j)
                Ps[w * 16 + hi * 4 + r][j * 16 + lo] = f2bf(sa[j][r]);
        __syncthreads();

#pragma unroll
        for (int ks = 0; ks < 2; ++ks) {
            short8 af = *(const short8*)&Ps[w * 16 + lo][ks * 32 + hi * 8];
#pragma unroll
            for (int n = 0; n < 8; ++n) {
                short8 bv = *(const short8*)&Vt[n * 16 + lo][ks * 32 + hi * 8];
                o[n] = __builtin_amdgcn_mfma_f32_16x16x32_bf16(af, bv, o[n], 0, 0, 0);
            }
        }
        __syncthreads();
    }

    if (nsplit == 1) {
#pragma unroll
        for (int n = 0; n < 8; ++n) {
            int h = n * 16 + lo;
#pragma unroll
            for (int r = 0; r < 4; ++r) {
                int row = qrow_base + r;
                out[((size_t)b * T + row) * HD + h] = o[n][r] / lrow[r];
            }
        }
    } else {
        const size_t slot = (size_t)(b * 32 + qt) * 4 + s;
        float* po = part_o + slot * (QB * HD);
#pragma unroll
        for (int n = 0; n < 8; ++n) {
            int h = n * 16 + lo;
#pragma unroll
            for (int r = 0; r < 4; ++r)
                po[(w * 16 + hi * 4 + r) * HD + h] = o[n][r];
        }
        if (lo == 0) {
            float* pm = part_ml + slot * (QB * 2);
#pragma unroll
            for (int r = 0; r < 4; ++r) {
                pm[(w * 16 + hi * 4 + r) * 2 + 0] = mrow[r];
                pm[(w * 16 + hi * 4 + r) * 2 + 1] = lrow[r];
            }
        }
    }
}

// ---------------------------------------------------------------------------
// Kernel 3: combine split partials (only q-tiles 8..31 have >1 split)
// ---------------------------------------------------------------------------
__global__ __launch_bounds__(256) void attn_combine(
    const float* __restrict__ part_o, const float* __restrict__ part_ml,
    float* __restrict__ out)
{
    const int qt = 8 + blockIdx.x;     // 8..31
    const int b  = blockIdx.y;
    const int ns = qt / 8 + 1;         // 2..4
    const int tid = threadIdx.x;
    const int row = tid >> 2;          // 0..63
    const int c0  = (tid & 3) * 32;
    const size_t slot0 = (size_t)(b * 32 + qt) * 4;

    float mi[4], li[4];
    float m = -1e30f;
#pragma unroll 4
    for (int i = 0; i < ns; ++i) {
        mi[i] = part_ml[(slot0 + i) * (QB * 2) + row * 2 + 0];
        li[i] = part_ml[(slot0 + i) * (QB * 2) + row * 2 + 1];
        m = fmaxf(m, mi[i]);
    }
    float L = 0.0f, f[4];
#pragma unroll 4
    for (int i = 0; i < ns; ++i) {
        f[i] = exp2f(mi[i] - m);
        L += li[i] * f[i];
    }
    const float inv = 1.0f / L;

    float4 acc[8];
#pragma unroll
    for (int k = 0; k < 8; ++k) acc[k] = make_float4(0.f, 0.f, 0.f, 0.f);
#pragma unroll 4
    for (int i = 0; i < ns; ++i) {
        const float4* src = (const float4*)(part_o + (slot0 + i) * (QB * HD) + row * HD + c0);
#pragma unroll
        for (int k = 0; k < 8; ++k) {
            float4 v = src[k];
            acc[k].x += f[i] * v.x; acc[k].y += f[i] * v.y;
            acc[k].z += f[i] * v.z; acc[k].w += f[i] * v.w;
        }
    }
    float4* dst = (float4*)(out + ((size_t)b * T + qt * QB + row) * HD + c0);
#pragma unroll
    for (int k = 0; k < 8; ++k) {
        float4 v = acc[k];
        dst[k] = make_float4(v.x * inv, v.y * inv, v.z * inv, v.w * inv);
    }
}

// ---------------------------------------------------------------------------
extern "C" void kernel_launch(void* const* d_in, const int* in_sizes, int n_in,
                              void* d_out, int out_size, void* d_ws, size_t ws_size,
                              hipStream_t stream)
{
    const float* x  = (const float*)d_in[0];
    const float* Wq = (const float*)d_in[1];
    const float* Wk = (const float*)d_in[2];
    const float* Wv = (const float*)d_in[3];
    float* out = (float*)d_out;

    // ws layout (bytes)
    const size_t off_Wb = 0;
    const size_t off_Q  = off_Wb + (size_t)NW * EMB * 2;        // 1.5 MB
    const size_t off_K  = off_Q  + (size_t)M * HD * 2;          // +4 MB
    const size_t off_V  = off_K  + (size_t)M * HD * 2;
    const size_t off_po = off_V  + (size_t)M * HD * 2;
    const size_t off_ml = off_po + (size_t)1024 * QB * HD * 4;  // 32 MB partials
    const size_t total  = off_ml + (size_t)1024 * QB * 2 * 4;

    char* ws = (char*)d_ws;
    unsigned short* Wb  = (unsigned short*)(ws + off_Wb);
    unsigned short* Qb  = (unsigned short*)(ws + off_Q);
    unsigned short* Kb  = (unsigned short*)(ws + off_K);
    unsigned short* VtG = (unsigned short*)(ws + off_V);
    float* part_o  = (float*)(ws + off_po);
    float* part_ml = (float*)(ws + off_ml);

    const int use_split = (ws_size >= total) ? 1 : 0;

    conv_w<<<dim3((NW * EMB) / (256 * 8)), 256, 0, stream>>>(Wq, Wk, Wv, Wb);
    qkv_proj<<<dim3(512), 256, 0, stream>>>(x, Wb, Qb, Kb, VtG);
    attn_fwd<<<dim3(use_split ? 80 : 32, B), 256, 0, stream>>>(
        Qb, Kb, VtG, out, part_o, part_ml, use_split);
    if (use_split)
        attn_combine<<<dim3(24, B), 256, 0, stream>>>(part_o, part_ml, out);
}